// Round 6
// baseline (861.983 us; speedup 1.0000x reference)
//
#include <hip/hip_runtime.h>
#include <hip/hip_bf16.h>

#define NN 4096
#define BB 8
#define LAT 32
#define ELLCAP 128

// ---------------- ELL build: extract sparse structure of A0 ----------------
__global__ void ell_build(const float* __restrict__ A, int* __restrict__ col,
                          float* __restrict__ val, int* __restrict__ nnz) {
  int row = blockIdx.x;
  int lane = threadIdx.x;  // 64
  const float* ar = A + (size_t)row * NN;
  int base = 0;
  for (int j0 = 0; j0 < NN; j0 += 64) {
    float a = ar[j0 + lane];
    unsigned long long m = __ballot(a != 0.0f);
    if (a != 0.0f) {
      int pos = base + __popcll(m & ((1ull << lane) - 1ull));
      if (pos < ELLCAP) {
        col[(size_t)row * ELLCAP + pos] = j0 + lane;
        val[(size_t)row * ELLCAP + pos] = a;
      }
    }
    base += __popcll(m);
  }
  if (lane == 0) nnz[row] = base < ELLCAP ? base : ELLCAP;
}

// ---------------- p-vector inverse norms ----------------
__global__ void pnorm_kernel(const float* __restrict__ p1, const float* __restrict__ p2,
                             float* __restrict__ invn) {
  int lane = threadIdx.x;  // 64
  float s1 = 0.f, s2 = 0.f;
  for (int i = lane; i < 128; i += 64) s1 += p1[i] * p1[i];
  { float v = p2[lane]; s2 = v * v; }
  for (int off = 32; off; off >>= 1) { s1 += __shfl_down(s1, off); s2 += __shfl_down(s2, off); }
  if (lane == 0) { invn[0] = rsqrtf(s1); invn[1] = rsqrtf(s2); }
}

// ---------------- dense GEMM: out[M,C] = in[M,K] @ W[K,C], optional row map (scatter/unpool) ----
// grid (M/64, B), block (32,8). map: out-row -> src-row (-1 => zero row).
template <int CT>
__global__ __launch_bounds__(256) void gemm_kernel(
    const float* __restrict__ in, const float* __restrict__ W, float* __restrict__ out,
    int M, int K, long inB, long outB, const int* __restrict__ map, int mapB) {
  const int C = CT * 32;
  const int KT = 64, LDI = KT + 4;
  extern __shared__ float lds[];
  float* Wl = lds;            // [KT][C]
  float* inT = lds + KT * C;  // [64][LDI]
  int b = blockIdx.y;
  const float* inb = in + (size_t)b * inB;
  float* outb = out + (size_t)b * outB;
  const int* mapb = map ? map + (size_t)b * mapB : nullptr;
  int tx = threadIdx.x, ty = threadIdx.y;
  int row0 = blockIdx.x * 64;
  float acc[8][CT];
#pragma unroll
  for (int i = 0; i < 8; i++)
#pragma unroll
    for (int j = 0; j < CT; j++) acc[i][j] = 0.f;
  for (int kt = 0; kt < K; kt += KT) {
    int kc = (K - kt < KT) ? (K - kt) : KT;
    for (int r = ty; r < kc; r += 8)
      for (int c = tx; c < C; c += 32) Wl[r * C + c] = W[(size_t)(kt + r) * C + c];
    for (int r = ty; r < 64; r += 8) {
      int grow = row0 + r;
      int src = grow;
      if (mapb) src = mapb[grow];
      if (src >= 0) {
        const float* ib = inb + (size_t)src * K + kt;
        for (int k = tx; k < kc; k += 32) inT[r * LDI + k] = ib[k];
      } else {
        for (int k = tx; k < kc; k += 32) inT[r * LDI + k] = 0.f;
      }
    }
    __syncthreads();
    for (int k = 0; k < kc; k += 4) {
      float4 a[8];
#pragma unroll
      for (int i = 0; i < 8; i++) a[i] = *(const float4*)&inT[(ty + i * 8) * LDI + k];
#pragma unroll
      for (int kk = 0; kk < 4; kk++) {
#pragma unroll
        for (int j = 0; j < CT; j++) {
          float w = Wl[(k + kk) * C + tx + j * 32];
#pragma unroll
          for (int i = 0; i < 8; i++) {
            float av = ((const float*)&a[i])[kk];
            acc[i][j] = fmaf(av, w, acc[i][j]);
          }
        }
      }
    }
    __syncthreads();
  }
#pragma unroll
  for (int i = 0; i < 8; i++) {
    int grow = row0 + ty + i * 8;
#pragma unroll
    for (int j = 0; j < CT; j++) outb[(size_t)grow * C + tx + j * 32] = acc[i][j];
  }
}

// ---------------- SpMM over A0's ELL with row-map / col-inverse-map ----------------
// grid (M, B), block C threads. act: 0=none 1=relu 2=softplus 3=VAE epilogue.
__global__ void spmm_kernel(
    const int* __restrict__ ecol, const float* __restrict__ evals, const int* __restrict__ ennz,
    const int* __restrict__ rowmap, int rowmapB,
    const int* __restrict__ colinv, int colinvB,
    const float* __restrict__ Y, long yB, const float* __restrict__ bias,
    float* __restrict__ out, long outB, int C, int act,
    const float* __restrict__ eps, float* __restrict__ meanOut,
    float* __restrict__ logvarOut, float* __restrict__ zOut) {
  __shared__ float hl[64];
  int row = blockIdx.x, b = blockIdx.y, t = threadIdx.x;
  int grow = rowmap ? rowmap[(size_t)b * rowmapB + row] : row;
  const int* ci = colinv ? colinv + (size_t)b * colinvB : nullptr;
  const float* Yb = Y + (size_t)b * yB;
  int n = ennz[grow];
  const int* cp = ecol + (size_t)grow * ELLCAP;
  const float* vp = evals + (size_t)grow * ELLCAP;
  float acc = 0.f;
  for (int e = 0; e < n; e++) {
    int c = cp[e];
    int li = ci ? ci[c] : c;
    if (li >= 0) acc = fmaf(vp[e], Yb[(size_t)li * C + t], acc);
  }
  acc += bias[t];
  if (act == 1) {
    acc = fmaxf(acc, 0.f);
  } else if (act == 2) {
    acc = fmaxf(acc, 0.f) + log1pf(expf(-fabsf(acc)));
  } else if (act == 3) {
    hl[t] = acc;
    __syncthreads();
    size_t o = ((size_t)b * 1024 + row) * LAT;
    if (t < LAT) {
      float lv = hl[t + LAT];
      meanOut[o + t] = acc;
      zOut[o + t] = fmaf(expf(0.5f * lv), eps[o + t], acc);
    } else {
      logvarOut[o + (t - LAT)] = acc;
    }
    return;
  }
  out[(size_t)b * outB + (size_t)row * C + t] = acc;
}

// ---------------- y = X @ p (row dots) ----------------
__global__ void ydot_kernel(const float* __restrict__ X, long xB, const float* __restrict__ p,
                            int C, int M, float* __restrict__ y, long yB) {
  int wv = threadIdx.x >> 6, lane = threadIdx.x & 63;
  int row = blockIdx.x * 4 + wv;
  int b = blockIdx.y;
  const float* xr = X + (size_t)b * xB + (size_t)row * C;
  float s = 0.f;
  for (int c = lane; c < C; c += 64) s += xr[c] * p[c];
  for (int off = 32; off; off >>= 1) s += __shfl_down(s, off);
  if (lane == 0) y[(size_t)b * yB + row] = s;
}

// ---------------- gather + tanh gate: out[r] = X[idx[r]] * tanh(y[idx[r]]*invn) ----------------
__global__ void gather_gate(const float* __restrict__ X, long xB,
                            const int* __restrict__ idx, int idxB,
                            const float* __restrict__ y, long yB,
                            const float* __restrict__ invn, int which,
                            float* __restrict__ out, long outB, int C) {
  int row = blockIdx.x, b = blockIdx.y, t = threadIdx.x;
  int src = idx[(size_t)b * idxB + row];
  float gate = tanhf(y[(size_t)b * yB + src] * invn[which]);
  out[(size_t)b * outB + (size_t)row * C + t] =
      X[(size_t)b * xB + (size_t)src * C + t] * gate;
}

// ---------------- top-k: bitonic sort for threshold + ordered compaction ----------------
// one block (1024 threads) per batch. n in {4096,2048}, k = n/2.
__global__ __launch_bounds__(1024) void topk_kernel(
    const float* __restrict__ yIn, int yB, int n, int k,
    const int* __restrict__ prevIdx, int prevB,
    int* __restrict__ idxLoc, int idxB,
    int* __restrict__ invLoc, int invB,
    int* __restrict__ gIdx, int gIdxB,
    int* __restrict__ gInv, int gInvB) {
  __shared__ float sv[4096];
  __shared__ int si[1024];
  __shared__ float stv;
  int b = blockIdx.x, tid = threadIdx.x;
  const float* y = yIn + (size_t)b * yB;
  for (int i = tid; i < n; i += 1024) sv[i] = y[i];
  int* invb = invLoc + (size_t)b * invB;
  for (int i = tid; i < n; i += 1024) invb[i] = -1;
  int* ginvb = gInv ? gInv + (size_t)b * gInvB : nullptr;
  if (ginvb)
    for (int i = tid; i < NN; i += 1024) ginvb[i] = -1;
  __syncthreads();
  // bitonic ascending sort of sv[0..n)
  for (int ks = 2; ks <= n; ks <<= 1) {
    for (int j = ks >> 1; j > 0; j >>= 1) {
      for (int i = tid; i < n; i += 1024) {
        int ixj = i ^ j;
        if (ixj > i) {
          float a = sv[i], c = sv[ixj];
          bool up = ((i & ks) == 0);
          if (up ? (a > c) : (a < c)) { sv[i] = c; sv[ixj] = a; }
        }
      }
      __syncthreads();
    }
  }
  if (tid == 0) stv = sv[n - k];  // k-th largest
  __syncthreads();
  float t = stv;
  int ipt = n >> 10;
  int i0 = tid * ipt;
  int locGt = 0, locEq = 0;
  for (int u = 0; u < ipt; u++) {
    float v = y[i0 + u];
    locGt += (v > t) ? 1 : 0;
    locEq += (v == t) ? 1 : 0;
  }
  int comb = (locGt << 13) | locEq;
  si[tid] = comb;
  __syncthreads();
  for (int off = 1; off < 1024; off <<= 1) {
    int vv = si[tid];
    int add = (tid >= off) ? si[tid - off] : 0;
    __syncthreads();
    si[tid] = vv + add;
    __syncthreads();
  }
  int incl = si[tid];
  int total = si[1023];
  int excl = incl - comb;
  int m = total >> 13;          // count strictly greater
  int needEq = k - m;           // fill remaining with == t, lowest index first
  int gtB = excl >> 13;
  int eqB = excl & 0x1FFF;
  int* idxb = idxLoc + (size_t)b * idxB;
  int* gidxb = gIdx ? gIdx + (size_t)b * gIdxB : nullptr;
  const int* prevb = prevIdx ? prevIdx + (size_t)b * prevB : nullptr;
  for (int u = 0; u < ipt; u++) {
    int i = i0 + u;
    float v = y[i];
    bool g = v > t;
    bool e = (v == t);
    bool sel = g || (e && eqB < needEq);
    if (sel) {
      int pos = gtB + (eqB < needEq ? eqB : needEq);
      idxb[pos] = i;
      invb[i] = pos;
      int gi = prevb ? prevb[i] : i;
      if (gidxb) gidxb[pos] = gi;
      if (ginvb) ginvb[gi] = pos;
    }
    gtB += g ? 1 : 0;
    eqB += e ? 1 : 0;
  }
}

// ---------------- host side ----------------
static inline void launch_gemm(const float* in, const float* W, float* out, int M, int K, int C,
                               long inB, long outB, const int* map, int mapB, hipStream_t s) {
  dim3 g(M / 64, BB), bl(32, 8);
  size_t lds = (size_t)(64 * C + 64 * 68) * 4;
  if (C == 64)
    gemm_kernel<2><<<g, bl, lds, s>>>(in, W, out, M, K, inB, outB, map, mapB);
  else if (C == 96)
    gemm_kernel<3><<<g, bl, lds, s>>>(in, W, out, M, K, inB, outB, map, mapB);
  else
    gemm_kernel<4><<<g, bl, lds, s>>>(in, W, out, M, K, inB, outB, map, mapB);
}

static inline void launch_spmm(const int* ecol, const float* evals, const int* ennz,
                               const int* rowmap, int rowmapB, const int* colinv, int colinvB,
                               const float* Y, long yB, const float* bias, float* out, long outB,
                               int M, int C, int act, hipStream_t s,
                               const float* eps = nullptr, float* meanOut = nullptr,
                               float* lvOut = nullptr, float* zOut = nullptr) {
  spmm_kernel<<<dim3(M, BB), dim3(C), 0, s>>>(ecol, evals, ennz, rowmap, rowmapB, colinv, colinvB,
                                              Y, yB, bias, out, outB, C, act, eps, meanOut, lvOut,
                                              zOut);
}

extern "C" void kernel_launch(void* const* d_in, const int* in_sizes, int n_in,
                              void* d_out, int out_size, void* d_ws, size_t ws_size,
                              hipStream_t stream) {
  const float* x = (const float*)d_in[0];
  const float* eps = (const float*)d_in[1];
  const float* A0 = (const float*)d_in[2];
  const float* W1 = (const float*)d_in[3];
  const float* b1 = (const float*)d_in[4];
  const float* p1 = (const float*)d_in[5];
  const float* W2 = (const float*)d_in[6];
  const float* b2 = (const float*)d_in[7];
  const float* p2 = (const float*)d_in[8];
  const float* Wlat = (const float*)d_in[9];
  const float* blat = (const float*)d_in[10];
  const float* Wd0 = (const float*)d_in[11];
  const float* bd0 = (const float*)d_in[12];
  const float* Wd1 = (const float*)d_in[13];
  const float* bd1 = (const float*)d_in[14];
  const float* Wd2 = (const float*)d_in[15];
  const float* bd2 = (const float*)d_in[16];
  const float* Wout = (const float*)d_in[17];
  const float* bout = (const float*)d_in[18];
  float* outp = (float*)d_out;
  float* meanOut = outp + (size_t)BB * 4096 * 64;
  float* logvarOut = meanOut + (size_t)BB * 1024 * 32;

  char* ws = (char*)d_ws;
  size_t off = 0;
  auto alloc = [&](size_t bytes) {
    void* p = ws + off;
    off = (off + bytes + 255) & ~(size_t)255;
    return p;
  };
  int* ell_col = (int*)alloc((size_t)NN * ELLCAP * 4);
  float* ell_val = (float*)alloc((size_t)NN * ELLCAP * 4);
  int* ell_nnz = (int*)alloc((size_t)NN * 4);
  float* invn = (float*)alloc(256);
  float* t0 = (float*)alloc((size_t)BB * 4096 * 128 * 4);
  float* t1 = (float*)alloc((size_t)BB * 4096 * 128 * 4);
  float* t2 = (float*)alloc((size_t)BB * 4096 * 128 * 4);
  float* y1 = (float*)alloc((size_t)BB * 4096 * 4);
  float* y2 = (float*)alloc((size_t)BB * 2048 * 4);
  int* idx1 = (int*)alloc((size_t)BB * 2048 * 4);
  int* inv1 = (int*)alloc((size_t)BB * 4096 * 4);
  int* idx2 = (int*)alloc((size_t)BB * 1024 * 4);
  int* inv2 = (int*)alloc((size_t)BB * 2048 * 4);
  int* gidx2 = (int*)alloc((size_t)BB * 1024 * 4);
  int* ginv2 = (int*)alloc((size_t)BB * 4096 * 4);
  float* zbuf = (float*)alloc((size_t)BB * 1024 * 32 * 4);

  // sparse structure + norms
  ell_build<<<dim3(NN), dim3(64), 0, stream>>>(A0, ell_col, ell_val, ell_nnz);
  pnorm_kernel<<<dim3(1), dim3(64), 0, stream>>>(p1, p2, invn);

  // ---- encoder level 0 ----
  launch_gemm(x, W1, t0, 4096, 64, 128, 4096l * 64, 4096l * 128, nullptr, 0, stream);
  launch_spmm(ell_col, ell_val, ell_nnz, nullptr, 0, nullptr, 0, t0, 4096l * 128, b1, t1,
              4096l * 128, 4096, 128, 1, stream);
  ydot_kernel<<<dim3(1024, BB), dim3(256), 0, stream>>>(t1, 4096l * 128, p1, 128, 4096, y1, 4096);
  topk_kernel<<<dim3(BB), dim3(1024), 0, stream>>>(y1, 4096, 4096, 2048, nullptr, 0, idx1, 2048,
                                                   inv1, 4096, nullptr, 0, nullptr, 0);
  gather_gate<<<dim3(2048, BB), dim3(128), 0, stream>>>(t1, 4096l * 128, idx1, 2048, y1, 4096,
                                                        invn, 0, t2, 2048l * 128, 128);

  // ---- encoder level 1 ----
  launch_gemm(t2, W2, t0, 2048, 128, 64, 2048l * 128, 2048l * 64, nullptr, 0, stream);
  launch_spmm(ell_col, ell_val, ell_nnz, idx1, 2048, inv1, 4096, t0, 2048l * 64, b2, t1,
              2048l * 64, 2048, 64, 1, stream);
  ydot_kernel<<<dim3(512, BB), dim3(256), 0, stream>>>(t1, 2048l * 64, p2, 64, 2048, y2, 2048);
  topk_kernel<<<dim3(BB), dim3(1024), 0, stream>>>(y2, 2048, 2048, 1024, idx1, 2048, idx2, 1024,
                                                   inv2, 2048, gidx2, 1024, ginv2, 4096);
  gather_gate<<<dim3(1024, BB), dim3(64), 0, stream>>>(t1, 2048l * 64, idx2, 1024, y2, 2048, invn,
                                                       1, t2, 1024l * 64, 64);

  // ---- latent + reparameterize (writes mean/logvar to d_out, z to ws) ----
  launch_gemm(t2, Wlat, t0, 1024, 64, 64, 1024l * 64, 1024l * 64, nullptr, 0, stream);
  launch_spmm(ell_col, ell_val, ell_nnz, gidx2, 1024, ginv2, 4096, t0, 1024l * 64, blat, nullptr,
              0, 1024, 64, 3, stream, eps, meanOut, logvarOut, zbuf);

  // ---- decoder ----
  launch_gemm(zbuf, Wd0, t0, 1024, 32, 64, 1024l * 32, 1024l * 64, nullptr, 0, stream);
  launch_spmm(ell_col, ell_val, ell_nnz, gidx2, 1024, ginv2, 4096, t0, 1024l * 64, bd0, t2,
              1024l * 64, 1024, 64, 1, stream);
  // unpool level2->level1 fused into scatter-GEMM (rows not in idx2 -> zero)
  launch_gemm(t2, Wd1, t0, 2048, 64, 96, 1024l * 64, 2048l * 96, inv2, 2048, stream);
  launch_spmm(ell_col, ell_val, ell_nnz, idx1, 2048, inv1, 4096, t0, 2048l * 96, bd1, t1,
              2048l * 96, 2048, 96, 1, stream);
  // unpool level1->level0 fused into scatter-GEMM
  launch_gemm(t1, Wd2, t0, 4096, 96, 128, 2048l * 96, 4096l * 128, inv1, 4096, stream);
  launch_spmm(ell_col, ell_val, ell_nnz, nullptr, 0, nullptr, 0, t0, 4096l * 128, bd2, t2,
              4096l * 128, 4096, 128, 1, stream);
  launch_gemm(t2, Wout, t0, 4096, 128, 64, 4096l * 128, 4096l * 64, nullptr, 0, stream);
  launch_spmm(ell_col, ell_val, ell_nnz, nullptr, 0, nullptr, 0, t0, 4096l * 64, bout, outp,
              4096l * 64, 4096, 64, 2, stream);
}

// Round 11
// 555.966 us; speedup vs baseline: 1.5504x; 1.5504x over previous
//
#include <hip/hip_runtime.h>
#include <hip/hip_bf16.h>

#define NN 4096
#define BB 8
#define LAT 32
#define ELLCAP 128

// ---------------- ELL build: extract sparse structure of A0 ----------------
__global__ void ell_build(const float* __restrict__ A, int* __restrict__ col,
                          float* __restrict__ val, int* __restrict__ nnz) {
  int row = blockIdx.x;
  int lane = threadIdx.x;  // 64
  const float* ar = A + (size_t)row * NN;
  int base = 0;
  for (int j0 = 0; j0 < NN; j0 += 64) {
    float a = ar[j0 + lane];
    unsigned long long m = __ballot(a != 0.0f);
    if (a != 0.0f) {
      int pos = base + __popcll(m & ((1ull << lane) - 1ull));
      if (pos < ELLCAP) {
        col[(size_t)row * ELLCAP + pos] = j0 + lane;
        val[(size_t)row * ELLCAP + pos] = a;
      }
    }
    base += __popcll(m);
  }
  if (lane == 0) nnz[row] = base < ELLCAP ? base : ELLCAP;
}

// ---------------- p-vector inverse norms ----------------
__global__ void pnorm_kernel(const float* __restrict__ p1, const float* __restrict__ p2,
                             float* __restrict__ invn) {
  int lane = threadIdx.x;  // 64
  float s1 = 0.f, s2 = 0.f;
  for (int i = lane; i < 128; i += 64) s1 += p1[i] * p1[i];
  { float v = p2[lane]; s2 = v * v; }
  for (int off = 32; off; off >>= 1) { s1 += __shfl_down(s1, off); s2 += __shfl_down(s2, off); }
  if (lane == 0) { invn[0] = rsqrtf(s1); invn[1] = rsqrtf(s2); }
}

// ---------------- dense GEMM with optional row map (gather/unpool-scatter) + tanh gate ----
// grid (M/64, B), block (32,8). map: out-row -> src-row (-1 => zero row).
// gateY: per-src pooling score; row scaled by tanh(gateY[src]*invn[which]).
template <int CT>
__global__ __launch_bounds__(256) void gemm_kernel(
    const float* __restrict__ in, const float* __restrict__ W, float* __restrict__ out,
    int M, int K, long inB, long outB, const int* __restrict__ map, int mapB,
    const float* __restrict__ gateY, long gyB, const float* __restrict__ invn, int which) {
  const int C = CT * 32;
  const int KT = 64, LDI = KT + 4;
  extern __shared__ float lds[];
  float* Wl = lds;            // [KT][C]
  float* inT = lds + KT * C;  // [64][LDI]
  int b = blockIdx.y;
  const float* inb = in + (size_t)b * inB;
  float* outb = out + (size_t)b * outB;
  const int* mapb = map ? map + (size_t)b * mapB : nullptr;
  int tx = threadIdx.x, ty = threadIdx.y;
  int row0 = blockIdx.x * 64;
  float acc[8][CT];
#pragma unroll
  for (int i = 0; i < 8; i++)
#pragma unroll
    for (int j = 0; j < CT; j++) acc[i][j] = 0.f;
  for (int kt = 0; kt < K; kt += KT) {
    int kc = (K - kt < KT) ? (K - kt) : KT;
    for (int r = ty; r < kc; r += 8)
      for (int c = tx; c < C; c += 32) Wl[r * C + c] = W[(size_t)(kt + r) * C + c];
    for (int r = ty; r < 64; r += 8) {
      int grow = row0 + r;
      int src = grow;
      if (mapb) src = mapb[grow];
      if (src >= 0) {
        float gate = 1.f;
        if (gateY) gate = tanhf(gateY[(size_t)b * gyB + src] * invn[which]);
        const float* ib = inb + (size_t)src * K + kt;
        for (int k = tx; k < kc; k += 32) inT[r * LDI + k] = ib[k] * gate;
      } else {
        for (int k = tx; k < kc; k += 32) inT[r * LDI + k] = 0.f;
      }
    }
    __syncthreads();
    for (int k = 0; k < kc; k += 4) {
      float4 a[8];
#pragma unroll
      for (int i = 0; i < 8; i++) a[i] = *(const float4*)&inT[(ty + i * 8) * LDI + k];
#pragma unroll
      for (int kk = 0; kk < 4; kk++) {
#pragma unroll
        for (int j = 0; j < CT; j++) {
          float w = Wl[(k + kk) * C + tx + j * 32];
#pragma unroll
          for (int i = 0; i < 8; i++) {
            float av = ((const float*)&a[i])[kk];
            acc[i][j] = fmaf(av, w, acc[i][j]);
          }
        }
      }
    }
    __syncthreads();
  }
#pragma unroll
  for (int i = 0; i < 8; i++) {
    int grow = row0 + ty + i * 8;
#pragma unroll
    for (int j = 0; j < CT; j++) outb[(size_t)grow * C + tx + j * 32] = acc[i][j];
  }
}

// ---------------- SpMM v2: XCD-pinned batch, LDS edge staging, 8-way MLP unroll ----
// grid (M*8) 1D: row = bid>>3, b = bid&7 (batch pinned to one XCD's L2).
// block C threads. act: 0=none 1=relu 2=softplus 3=VAE epilogue.
// Optional fused ydot: yOut[row] = dot(activated_row, pvec) (raw, no invn).
__global__ void spmm_kernel(
    const int* __restrict__ ecol, const float* __restrict__ evals, const int* __restrict__ ennz,
    const int* __restrict__ rowmap, int rowmapB,
    const int* __restrict__ colinv, int colinvB,
    const float* __restrict__ Y, long yB, const float* __restrict__ bias,
    float* __restrict__ out, long outB, int C, int act,
    const float* __restrict__ eps, float* __restrict__ meanOut,
    float* __restrict__ logvarOut, float* __restrict__ zOut,
    const float* __restrict__ pvec, float* __restrict__ yOut, long yOutB) {
  __shared__ int scol[ELLCAP];
  __shared__ float sval[ELLCAP];
  __shared__ float red[128];
  int bid = blockIdx.x;
  int row = bid >> 3, b = bid & 7;
  int t = threadIdx.x;
  int grow = rowmap ? rowmap[(size_t)b * rowmapB + row] : row;
  int n = ennz[grow];
  const int* cp = ecol + (size_t)grow * ELLCAP;
  const float* vp = evals + (size_t)grow * ELLCAP;
  const int* ci = colinv ? colinv + (size_t)b * colinvB : nullptr;
  // stage translated edge list (col -> pooled local index; dropped -> weight 0)
  for (int e = t; e < n; e += C) {
    int c = cp[e];
    int li = ci ? ci[c] : c;
    float w = vp[e];
    if (li < 0) { li = 0; w = 0.f; }
    scol[e] = li;
    sval[e] = w;
  }
  __syncthreads();
  const float* Yb = Y + (size_t)b * yB;
  float acc = 0.f;
  int e = 0;
  for (; e + 8 <= n; e += 8) {
    const float* ap[8];
    float w[8], pv[8];
#pragma unroll
    for (int u = 0; u < 8; u++) {
      ap[u] = Yb + (size_t)scol[e + u] * C + t;
      w[u] = sval[e + u];
    }
#pragma unroll
    for (int u = 0; u < 8; u++) pv[u] = *ap[u];
#pragma unroll
    for (int u = 0; u < 8; u++) acc = fmaf(w[u], pv[u], acc);
  }
  for (; e < n; e++) acc = fmaf(sval[e], Yb[(size_t)scol[e] * C + t], acc);
  acc += bias[t];
  if (act == 1) {
    acc = fmaxf(acc, 0.f);
  } else if (act == 2) {
    acc = fmaxf(acc, 0.f) + log1pf(expf(-fabsf(acc)));
  } else if (act == 3) {
    red[t] = acc;
    __syncthreads();
    size_t o = ((size_t)b * 1024 + row) * LAT;
    if (t < LAT) {
      float lv = red[t + LAT];
      meanOut[o + t] = acc;
      zOut[o + t] = fmaf(expf(0.5f * lv), eps[o + t], acc);
    } else {
      logvarOut[o + (t - LAT)] = acc;
    }
    return;
  }
  out[(size_t)b * outB + (size_t)row * C + t] = acc;
  if (yOut) {  // fused pooling-score dot
    red[t] = acc * pvec[t];
    __syncthreads();
    for (int st = 64; st > 0; st >>= 1) {
      if (t < st && t + st < C) red[t] += red[t + st];
      __syncthreads();
    }
    if (t == 0) yOut[(size_t)b * yOutB + row] = red[0];
  }
}

// ---------------- top-k v2: radix select + ordered compaction ----------------
// one block (1024 threads) per batch. n in {4096,2048}, k = n/2.
__global__ __launch_bounds__(1024) void topk_kernel(
    const float* __restrict__ yIn, int yB, int n, int k,
    const int* __restrict__ prevIdx, int prevB,
    int* __restrict__ idxLoc, int idxB,
    int* __restrict__ invLoc, int invB,
    int* __restrict__ gIdx, int gIdxB,
    int* __restrict__ gInv, int gInvB) {
  __shared__ unsigned int sk[4096];
  __shared__ unsigned int hist[256];
  __shared__ int si[1024];
  __shared__ int s_bin, s_cum;
  int b = blockIdx.x, tid = threadIdx.x;
  const float* y = yIn + (size_t)b * yB;
  // monotonic float->uint key (larger float <=> larger key)
  for (int i = tid; i < n; i += 1024) {
    unsigned u = __float_as_uint(y[i]);
    sk[i] = (u & 0x80000000u) ? ~u : (u | 0x80000000u);
  }
  int* invb = invLoc + (size_t)b * invB;
  for (int i = tid; i < n; i += 1024) invb[i] = -1;
  int* ginvb = gInv ? gInv + (size_t)b * gInvB : nullptr;
  if (ginvb)
    for (int i = tid; i < NN; i += 1024) ginvb[i] = -1;
  __syncthreads();
  // radix select: find k-th largest key (4 passes of 8 bits)
  unsigned prefix = 0;
  int kneed = k, countGt = 0;
  for (int shift = 24; shift >= 0; shift -= 8) {
    if (tid < 256) hist[tid] = 0;
    __syncthreads();
    unsigned pmask = (shift == 24) ? 0u : (0xFFFFFFFFu << (shift + 8));
    for (int i = tid; i < n; i += 1024) {
      unsigned key = sk[i];
      if ((key & pmask) == prefix) atomicAdd(&hist[(key >> shift) & 255], 1u);
    }
    __syncthreads();
    if (tid < 256) si[tid] = (int)hist[tid];
    __syncthreads();
    // suffix sums: si[bin] = sum hist[bin..255]
    for (int off = 1; off < 256; off <<= 1) {
      int v = 0;
      if (tid < 256) { v = si[tid]; if (tid + off < 256) v += si[tid + off]; }
      __syncthreads();
      if (tid < 256) si[tid] = v;
      __syncthreads();
    }
    if (tid < 256) {
      int cumAbove = (tid < 255) ? si[tid + 1] : 0;
      if (cumAbove < kneed && kneed <= cumAbove + (int)hist[tid]) {
        s_bin = tid;
        s_cum = cumAbove;
      }
    }
    __syncthreads();
    int bin = s_bin, cumAbove = s_cum;
    countGt += cumAbove;
    kneed -= cumAbove;
    prefix |= ((unsigned)bin << shift);
    __syncthreads();
  }
  unsigned tkey = prefix;
  int needEq = k - countGt;
  // ordered compaction (node order preserved; ties -> lowest index first)
  int ipt = n >> 10;
  int i0 = tid * ipt;
  int locGt = 0, locEq = 0;
  for (int u = 0; u < ipt; u++) {
    unsigned key = sk[i0 + u];
    locGt += (key > tkey) ? 1 : 0;
    locEq += (key == tkey) ? 1 : 0;
  }
  int comb = (locGt << 13) | locEq;
  si[tid] = comb;
  __syncthreads();
  for (int off = 1; off < 1024; off <<= 1) {
    int vv = si[tid];
    int add = (tid >= off) ? si[tid - off] : 0;
    __syncthreads();
    si[tid] = vv + add;
    __syncthreads();
  }
  int excl = si[tid] - comb;
  int gtB = excl >> 13;
  int eqB = excl & 0x1FFF;
  int* idxb = idxLoc + (size_t)b * idxB;
  int* gidxb = gIdx ? gIdx + (size_t)b * gIdxB : nullptr;
  const int* prevb = prevIdx ? prevIdx + (size_t)b * prevB : nullptr;
  for (int u = 0; u < ipt; u++) {
    int i = i0 + u;
    unsigned key = sk[i];
    bool g = key > tkey;
    bool e = (key == tkey);
    bool sel = g || (e && eqB < needEq);
    if (sel) {
      int pos = gtB + (eqB < needEq ? eqB : needEq);
      idxb[pos] = i;
      invb[i] = pos;
      int gi = prevb ? prevb[i] : i;
      if (gidxb) gidxb[pos] = gi;
      if (ginvb) ginvb[gi] = pos;
    }
    gtB += g ? 1 : 0;
    eqB += e ? 1 : 0;
  }
}

// ---------------- host side ----------------
static inline void launch_gemm(const float* in, const float* W, float* out, int M, int K, int C,
                               long inB, long outB, const int* map, int mapB, hipStream_t s,
                               const float* gateY = nullptr, long gyB = 0,
                               const float* invn = nullptr, int which = 0) {
  dim3 g(M / 64, BB), bl(32, 8);
  size_t lds = (size_t)(64 * C + 64 * 68) * 4;
  if (C == 64)
    gemm_kernel<2><<<g, bl, lds, s>>>(in, W, out, M, K, inB, outB, map, mapB, gateY, gyB, invn, which);
  else if (C == 96)
    gemm_kernel<3><<<g, bl, lds, s>>>(in, W, out, M, K, inB, outB, map, mapB, gateY, gyB, invn, which);
  else
    gemm_kernel<4><<<g, bl, lds, s>>>(in, W, out, M, K, inB, outB, map, mapB, gateY, gyB, invn, which);
}

static inline void launch_spmm(const int* ecol, const float* evals, const int* ennz,
                               const int* rowmap, int rowmapB, const int* colinv, int colinvB,
                               const float* Y, long yB, const float* bias, float* out, long outB,
                               int M, int C, int act, hipStream_t s,
                               const float* eps = nullptr, float* meanOut = nullptr,
                               float* lvOut = nullptr, float* zOut = nullptr,
                               const float* pvec = nullptr, float* yOut = nullptr, long yOutB = 0) {
  spmm_kernel<<<dim3(M * BB), dim3(C), 0, s>>>(ecol, evals, ennz, rowmap, rowmapB, colinv, colinvB,
                                               Y, yB, bias, out, outB, C, act, eps, meanOut, lvOut,
                                               zOut, pvec, yOut, yOutB);
}

extern "C" void kernel_launch(void* const* d_in, const int* in_sizes, int n_in,
                              void* d_out, int out_size, void* d_ws, size_t ws_size,
                              hipStream_t stream) {
  const float* x = (const float*)d_in[0];
  const float* eps = (const float*)d_in[1];
  const float* A0 = (const float*)d_in[2];
  const float* W1 = (const float*)d_in[3];
  const float* b1 = (const float*)d_in[4];
  const float* p1 = (const float*)d_in[5];
  const float* W2 = (const float*)d_in[6];
  const float* b2 = (const float*)d_in[7];
  const float* p2 = (const float*)d_in[8];
  const float* Wlat = (const float*)d_in[9];
  const float* blat = (const float*)d_in[10];
  const float* Wd0 = (const float*)d_in[11];
  const float* bd0 = (const float*)d_in[12];
  const float* Wd1 = (const float*)d_in[13];
  const float* bd1 = (const float*)d_in[14];
  const float* Wd2 = (const float*)d_in[15];
  const float* bd2 = (const float*)d_in[16];
  const float* Wout = (const float*)d_in[17];
  const float* bout = (const float*)d_in[18];
  float* outp = (float*)d_out;
  float* meanOut = outp + (size_t)BB * 4096 * 64;
  float* logvarOut = meanOut + (size_t)BB * 1024 * 32;

  char* ws = (char*)d_ws;
  size_t off = 0;
  auto alloc = [&](size_t bytes) {
    void* p = ws + off;
    off = (off + bytes + 255) & ~(size_t)255;
    return p;
  };
  int* ell_col = (int*)alloc((size_t)NN * ELLCAP * 4);
  float* ell_val = (float*)alloc((size_t)NN * ELLCAP * 4);
  int* ell_nnz = (int*)alloc((size_t)NN * 4);
  float* invn = (float*)alloc(256);
  float* t0 = (float*)alloc((size_t)BB * 4096 * 128 * 4);
  float* t1 = (float*)alloc((size_t)BB * 4096 * 128 * 4);
  float* t2 = (float*)alloc((size_t)BB * 4096 * 128 * 4);
  float* y1 = (float*)alloc((size_t)BB * 4096 * 4);
  float* y2 = (float*)alloc((size_t)BB * 2048 * 4);
  int* idx1 = (int*)alloc((size_t)BB * 2048 * 4);
  int* inv1 = (int*)alloc((size_t)BB * 4096 * 4);
  int* idx2 = (int*)alloc((size_t)BB * 1024 * 4);
  int* inv2 = (int*)alloc((size_t)BB * 2048 * 4);
  int* gidx2 = (int*)alloc((size_t)BB * 1024 * 4);
  int* ginv2 = (int*)alloc((size_t)BB * 4096 * 4);
  float* zbuf = (float*)alloc((size_t)BB * 1024 * 32 * 4);

  // sparse structure + norms
  ell_build<<<dim3(NN), dim3(64), 0, stream>>>(A0, ell_col, ell_val, ell_nnz);
  pnorm_kernel<<<dim3(1), dim3(64), 0, stream>>>(p1, p2, invn);

  // ---- encoder level 0 ----
  launch_gemm(x, W1, t0, 4096, 64, 128, 4096l * 64, 4096l * 128, nullptr, 0, stream);
  launch_spmm(ell_col, ell_val, ell_nnz, nullptr, 0, nullptr, 0, t0, 4096l * 128, b1, t1,
              4096l * 128, 4096, 128, 1, stream, nullptr, nullptr, nullptr, nullptr,
              p1, y1, 4096);
  topk_kernel<<<dim3(BB), dim3(1024), 0, stream>>>(y1, 4096, 4096, 2048, nullptr, 0, idx1, 2048,
                                                   inv1, 4096, nullptr, 0, nullptr, 0);

  // ---- encoder level 1 (gather + gate fused into GEMM) ----
  launch_gemm(t1, W2, t0, 2048, 128, 64, 4096l * 128, 2048l * 64, idx1, 2048, stream,
              y1, 4096, invn, 0);
  launch_spmm(ell_col, ell_val, ell_nnz, idx1, 2048, inv1, 4096, t0, 2048l * 64, b2, t1,
              2048l * 64, 2048, 64, 1, stream, nullptr, nullptr, nullptr, nullptr,
              p2, y2, 2048);
  topk_kernel<<<dim3(BB), dim3(1024), 0, stream>>>(y2, 2048, 2048, 1024, idx1, 2048, idx2, 1024,
                                                   inv2, 2048, gidx2, 1024, ginv2, 4096);

  // ---- latent + reparameterize (gather+gate fused; writes mean/logvar to d_out, z to ws) ----
  launch_gemm(t1, Wlat, t0, 1024, 64, 64, 2048l * 64, 1024l * 64, idx2, 1024, stream,
              y2, 2048, invn, 1);
  launch_spmm(ell_col, ell_val, ell_nnz, gidx2, 1024, ginv2, 4096, t0, 1024l * 64, blat, nullptr,
              0, 1024, 64, 3, stream, eps, meanOut, logvarOut, zbuf);

  // ---- decoder ----
  launch_gemm(zbuf, Wd0, t0, 1024, 32, 64, 1024l * 32, 1024l * 64, nullptr, 0, stream);
  launch_spmm(ell_col, ell_val, ell_nnz, gidx2, 1024, ginv2, 4096, t0, 1024l * 64, bd0, t2,
              1024l * 64, 1024, 64, 1, stream);
  // unpool level2->level1 fused into scatter-GEMM (rows not in idx2 -> zero)
  launch_gemm(t2, Wd1, t0, 2048, 64, 96, 1024l * 64, 2048l * 96, inv2, 2048, stream);
  launch_spmm(ell_col, ell_val, ell_nnz, idx1, 2048, inv1, 4096, t0, 2048l * 96, bd1, t1,
              2048l * 96, 2048, 96, 1, stream);
  // unpool level1->level0 fused into scatter-GEMM
  launch_gemm(t1, Wd2, t0, 4096, 96, 128, 2048l * 96, 4096l * 128, inv1, 4096, stream);
  launch_spmm(ell_col, ell_val, ell_nnz, nullptr, 0, nullptr, 0, t0, 4096l * 128, bd2, t2,
              4096l * 128, 4096, 128, 1, stream);
  launch_gemm(t2, Wout, t0, 4096, 128, 64, 4096l * 128, 4096l * 64, nullptr, 0, stream);
  launch_spmm(ell_col, ell_val, ell_nnz, nullptr, 0, nullptr, 0, t0, 4096l * 64, bout, outp,
              4096l * 64, 4096, 64, 2, stream);
}

// Round 12
// 499.350 us; speedup vs baseline: 1.7262x; 1.1134x over previous
//
#include <hip/hip_runtime.h>
#include <hip/hip_bf16.h>

#define NN 4096
#define BB 8
#define LAT 32
#define ELLCAP 128

// ---------------- ELL build: extract sparse structure of A0 ----------------
__global__ void ell_build(const float* __restrict__ A, int* __restrict__ col,
                          float* __restrict__ val, int* __restrict__ nnz) {
  int row = blockIdx.x;
  int lane = threadIdx.x;  // 64
  const float* ar = A + (size_t)row * NN;
  int base = 0;
  for (int j0 = 0; j0 < NN; j0 += 64) {
    float a = ar[j0 + lane];
    unsigned long long m = __ballot(a != 0.0f);
    if (a != 0.0f) {
      int pos = base + __popcll(m & ((1ull << lane) - 1ull));
      if (pos < ELLCAP) {
        col[(size_t)row * ELLCAP + pos] = j0 + lane;
        val[(size_t)row * ELLCAP + pos] = a;
      }
    }
    base += __popcll(m);
  }
  if (lane == 0) nnz[row] = base < ELLCAP ? base : ELLCAP;
}

// ---------------- p-vector inverse norms ----------------
__global__ void pnorm_kernel(const float* __restrict__ p1, const float* __restrict__ p2,
                             float* __restrict__ invn) {
  int lane = threadIdx.x;  // 64
  float s1 = 0.f, s2 = 0.f;
  for (int i = lane; i < 128; i += 64) s1 += p1[i] * p1[i];
  { float v = p2[lane]; s2 = v * v; }
  for (int off = 32; off; off >>= 1) { s1 += __shfl_down(s1, off); s2 += __shfl_down(s2, off); }
  if (lane == 0) { invn[0] = rsqrtf(s1); invn[1] = rsqrtf(s2); }
}

// ---------------- dense GEMM with optional row map (gather/unpool-scatter) + tanh gate ----
// grid (M/64, B), block (32,8). map: out-row -> src-row (-1 => zero row).
template <int CT>
__global__ __launch_bounds__(256) void gemm_kernel(
    const float* __restrict__ in, const float* __restrict__ W, float* __restrict__ out,
    int M, int K, long inB, long outB, const int* __restrict__ map, int mapB,
    const float* __restrict__ gateY, long gyB, const float* __restrict__ invn, int which) {
  const int C = CT * 32;
  const int KT = 64, LDI = KT + 4;
  extern __shared__ float lds[];
  float* Wl = lds;            // [KT][C]
  float* inT = lds + KT * C;  // [64][LDI]
  int b = blockIdx.y;
  const float* inb = in + (size_t)b * inB;
  float* outb = out + (size_t)b * outB;
  const int* mapb = map ? map + (size_t)b * mapB : nullptr;
  int tx = threadIdx.x, ty = threadIdx.y;
  int row0 = blockIdx.x * 64;
  float acc[8][CT];
#pragma unroll
  for (int i = 0; i < 8; i++)
#pragma unroll
    for (int j = 0; j < CT; j++) acc[i][j] = 0.f;
  for (int kt = 0; kt < K; kt += KT) {
    int kc = (K - kt < KT) ? (K - kt) : KT;
    for (int r = ty; r < kc; r += 8)
      for (int c = tx; c < C; c += 32) Wl[r * C + c] = W[(size_t)(kt + r) * C + c];
    for (int r = ty; r < 64; r += 8) {
      int grow = row0 + r;
      int src = grow;
      if (mapb) src = mapb[grow];
      if (src >= 0) {
        float gate = 1.f;
        if (gateY) gate = tanhf(gateY[(size_t)b * gyB + src] * invn[which]);
        const float* ib = inb + (size_t)src * K + kt;
        for (int k = tx; k < kc; k += 32) inT[r * LDI + k] = ib[k] * gate;
      } else {
        for (int k = tx; k < kc; k += 32) inT[r * LDI + k] = 0.f;
      }
    }
    __syncthreads();
    for (int k = 0; k < kc; k += 4) {
      float4 a[8];
#pragma unroll
      for (int i = 0; i < 8; i++) a[i] = *(const float4*)&inT[(ty + i * 8) * LDI + k];
#pragma unroll
      for (int kk = 0; kk < 4; kk++) {
#pragma unroll
        for (int j = 0; j < CT; j++) {
          float w = Wl[(k + kk) * C + tx + j * 32];
#pragma unroll
          for (int i = 0; i < 8; i++) {
            float av = ((const float*)&a[i])[kk];
            acc[i][j] = fmaf(av, w, acc[i][j]);
          }
        }
      }
    }
    __syncthreads();
  }
#pragma unroll
  for (int i = 0; i < 8; i++) {
    int grow = row0 + ty + i * 8;
#pragma unroll
    for (int j = 0; j < CT; j++) outb[(size_t)grow * C + tx + j * 32] = acc[i][j];
  }
}

// ---------------- SpMM v3: float4 lanes, XCD-pinned batch, 8-way MLP unroll ----
// C in {64,128}. L = C/4 lanes per row, R = 128/L rows per block.
// grid ((M/R)*8) 1D: rowblock = bid>>3, b = bid&7.
// act: 0=none 1=relu 2=softplus 3=VAE epilogue.
template <int C>
__global__ __launch_bounds__(128) void spmm_vec_kernel(
    const int* __restrict__ ecol, const float* __restrict__ evals, const int* __restrict__ ennz,
    const int* __restrict__ rowmap, int rowmapB,
    const int* __restrict__ colinv, int colinvB,
    const float* __restrict__ Y, long yB, const float* __restrict__ bias,
    float* __restrict__ out, long outB, int act,
    const float* __restrict__ eps, float* __restrict__ meanOut,
    float* __restrict__ logvarOut, float* __restrict__ zOut,
    const float* __restrict__ pvec, float* __restrict__ yOut, long yOutB) {
  constexpr int L = C / 4;
  constexpr int R = 128 / L;
  __shared__ int scol[R][ELLCAP];
  __shared__ float sval[R][ELLCAP];
  int bid = blockIdx.x;
  int rb = bid >> 3, b = bid & 7;
  int t = threadIdx.x;
  int rloc = t / L, lane = t % L;
  int row = rb * R + rloc;
  int grow = rowmap ? rowmap[(size_t)b * rowmapB + row] : row;
  int n = ennz[grow];
  const int* cp = ecol + (size_t)grow * ELLCAP;
  const float* vp = evals + (size_t)grow * ELLCAP;
  const int* ci = colinv ? colinv + (size_t)b * colinvB : nullptr;
  for (int e = lane; e < n; e += L) {
    int c = cp[e];
    int li = ci ? ci[c] : c;
    float w = vp[e];
    if (li < 0) { li = 0; w = 0.f; }
    scol[rloc][e] = li;
    sval[rloc][e] = w;
  }
  __syncthreads();
  const float* Yb = Y + (size_t)b * yB;
  float4 acc = {0.f, 0.f, 0.f, 0.f};
  int e = 0;
  for (; e + 8 <= n; e += 8) {
    float4 v[8];
    float w[8];
#pragma unroll
    for (int u = 0; u < 8; u++) {
      w[u] = sval[rloc][e + u];
      v[u] = *(const float4*)&Yb[(size_t)scol[rloc][e + u] * C + lane * 4];
    }
#pragma unroll
    for (int u = 0; u < 8; u++) {
      acc.x = fmaf(w[u], v[u].x, acc.x);
      acc.y = fmaf(w[u], v[u].y, acc.y);
      acc.z = fmaf(w[u], v[u].z, acc.z);
      acc.w = fmaf(w[u], v[u].w, acc.w);
    }
  }
  for (; e < n; e++) {
    float w = sval[rloc][e];
    float4 v = *(const float4*)&Yb[(size_t)scol[rloc][e] * C + lane * 4];
    acc.x = fmaf(w, v.x, acc.x);
    acc.y = fmaf(w, v.y, acc.y);
    acc.z = fmaf(w, v.z, acc.z);
    acc.w = fmaf(w, v.w, acc.w);
  }
  float4 bi = *(const float4*)&bias[lane * 4];
  acc.x += bi.x; acc.y += bi.y; acc.z += bi.z; acc.w += bi.w;
  if (act == 1) {
    acc.x = fmaxf(acc.x, 0.f); acc.y = fmaxf(acc.y, 0.f);
    acc.z = fmaxf(acc.z, 0.f); acc.w = fmaxf(acc.w, 0.f);
  } else if (act == 2) {
    acc.x = fmaxf(acc.x, 0.f) + log1pf(expf(-fabsf(acc.x)));
    acc.y = fmaxf(acc.y, 0.f) + log1pf(expf(-fabsf(acc.y)));
    acc.z = fmaxf(acc.z, 0.f) + log1pf(expf(-fabsf(acc.z)));
    acc.w = fmaxf(acc.w, 0.f) + log1pf(expf(-fabsf(acc.w)));
  } else if (act == 3) {
    // C=64: lanes 0..7 hold mean cols, lanes 8..15 hold logvar cols.
    int wl = t & 63;
    float4 lv;
    lv.x = __shfl(acc.x, wl + 8, 64);
    lv.y = __shfl(acc.y, wl + 8, 64);
    lv.z = __shfl(acc.z, wl + 8, 64);
    lv.w = __shfl(acc.w, wl + 8, 64);
    size_t o = ((size_t)b * 1024 + row) * LAT;
    if (lane < 8) {
      *(float4*)&meanOut[o + lane * 4] = acc;
      float4 ep = *(const float4*)&eps[o + lane * 4];
      float4 z;
      z.x = fmaf(expf(0.5f * lv.x), ep.x, acc.x);
      z.y = fmaf(expf(0.5f * lv.y), ep.y, acc.y);
      z.z = fmaf(expf(0.5f * lv.z), ep.z, acc.z);
      z.w = fmaf(expf(0.5f * lv.w), ep.w, acc.w);
      *(float4*)&zOut[o + lane * 4] = z;
    } else {
      *(float4*)&logvarOut[o + (lane - 8) * 4] = acc;
    }
    return;
  }
  *(float4*)&out[(size_t)b * outB + (size_t)row * C + lane * 4] = acc;
  if (yOut) {  // fused pooling-score dot, shfl tree within the row's L lanes
    float4 pv = *(const float4*)&pvec[lane * 4];
    float part = acc.x * pv.x + acc.y * pv.y + acc.z * pv.z + acc.w * pv.w;
#pragma unroll
    for (int off = L / 2; off > 0; off >>= 1) part += __shfl_down(part, off, 64);
    if (lane == 0) yOut[(size_t)b * yOutB + row] = part;
  }
}

// ---------------- SpMM scalar (C=96 path) ----------------
__global__ void spmm_kernel(
    const int* __restrict__ ecol, const float* __restrict__ evals, const int* __restrict__ ennz,
    const int* __restrict__ rowmap, int rowmapB,
    const int* __restrict__ colinv, int colinvB,
    const float* __restrict__ Y, long yB, const float* __restrict__ bias,
    float* __restrict__ out, long outB, int C, int act) {
  __shared__ int scol[ELLCAP];
  __shared__ float sval[ELLCAP];
  int bid = blockIdx.x;
  int row = bid >> 3, b = bid & 7;
  int t = threadIdx.x;
  int grow = rowmap ? rowmap[(size_t)b * rowmapB + row] : row;
  int n = ennz[grow];
  const int* cp = ecol + (size_t)grow * ELLCAP;
  const float* vp = evals + (size_t)grow * ELLCAP;
  const int* ci = colinv ? colinv + (size_t)b * colinvB : nullptr;
  for (int e = t; e < n; e += C) {
    int c = cp[e];
    int li = ci ? ci[c] : c;
    float w = vp[e];
    if (li < 0) { li = 0; w = 0.f; }
    scol[e] = li;
    sval[e] = w;
  }
  __syncthreads();
  const float* Yb = Y + (size_t)b * yB;
  float acc = 0.f;
  int e = 0;
  for (; e + 8 <= n; e += 8) {
    const float* ap[8];
    float w[8], pv[8];
#pragma unroll
    for (int u = 0; u < 8; u++) {
      ap[u] = Yb + (size_t)scol[e + u] * C + t;
      w[u] = sval[e + u];
    }
#pragma unroll
    for (int u = 0; u < 8; u++) pv[u] = *ap[u];
#pragma unroll
    for (int u = 0; u < 8; u++) acc = fmaf(w[u], pv[u], acc);
  }
  for (; e < n; e++) acc = fmaf(sval[e], Yb[(size_t)scol[e] * C + t], acc);
  acc += bias[t];
  if (act == 1) acc = fmaxf(acc, 0.f);
  out[(size_t)b * outB + (size_t)row * C + t] = acc;
}

// ---------------- top-k: radix select + ordered compaction ----------------
__global__ __launch_bounds__(1024) void topk_kernel(
    const float* __restrict__ yIn, int yB, int n, int k,
    const int* __restrict__ prevIdx, int prevB,
    int* __restrict__ idxLoc, int idxB,
    int* __restrict__ invLoc, int invB,
    int* __restrict__ gIdx, int gIdxB,
    int* __restrict__ gInv, int gInvB) {
  __shared__ unsigned int sk[4096];
  __shared__ unsigned int hist[256];
  __shared__ int si[1024];
  __shared__ int s_bin, s_cum;
  int b = blockIdx.x, tid = threadIdx.x;
  const float* y = yIn + (size_t)b * yB;
  for (int i = tid; i < n; i += 1024) {
    unsigned u = __float_as_uint(y[i]);
    sk[i] = (u & 0x80000000u) ? ~u : (u | 0x80000000u);
  }
  int* invb = invLoc + (size_t)b * invB;
  for (int i = tid; i < n; i += 1024) invb[i] = -1;
  int* ginvb = gInv ? gInv + (size_t)b * gInvB : nullptr;
  if (ginvb)
    for (int i = tid; i < NN; i += 1024) ginvb[i] = -1;
  __syncthreads();
  unsigned prefix = 0;
  int kneed = k, countGt = 0;
  for (int shift = 24; shift >= 0; shift -= 8) {
    if (tid < 256) hist[tid] = 0;
    __syncthreads();
    unsigned pmask = (shift == 24) ? 0u : (0xFFFFFFFFu << (shift + 8));
    for (int i = tid; i < n; i += 1024) {
      unsigned key = sk[i];
      if ((key & pmask) == prefix) atomicAdd(&hist[(key >> shift) & 255], 1u);
    }
    __syncthreads();
    if (tid < 256) si[tid] = (int)hist[tid];
    __syncthreads();
    for (int off = 1; off < 256; off <<= 1) {
      int v = 0;
      if (tid < 256) { v = si[tid]; if (tid + off < 256) v += si[tid + off]; }
      __syncthreads();
      if (tid < 256) si[tid] = v;
      __syncthreads();
    }
    if (tid < 256) {
      int cumAbove = (tid < 255) ? si[tid + 1] : 0;
      if (cumAbove < kneed && kneed <= cumAbove + (int)hist[tid]) {
        s_bin = tid;
        s_cum = cumAbove;
      }
    }
    __syncthreads();
    int bin = s_bin, cumAbove = s_cum;
    countGt += cumAbove;
    kneed -= cumAbove;
    prefix |= ((unsigned)bin << shift);
    __syncthreads();
  }
  unsigned tkey = prefix;
  int needEq = k - countGt;
  int ipt = n >> 10;
  int i0 = tid * ipt;
  int locGt = 0, locEq = 0;
  for (int u = 0; u < ipt; u++) {
    unsigned key = sk[i0 + u];
    locGt += (key > tkey) ? 1 : 0;
    locEq += (key == tkey) ? 1 : 0;
  }
  int comb = (locGt << 13) | locEq;
  si[tid] = comb;
  __syncthreads();
  for (int off = 1; off < 1024; off <<= 1) {
    int vv = si[tid];
    int add = (tid >= off) ? si[tid - off] : 0;
    __syncthreads();
    si[tid] = vv + add;
    __syncthreads();
  }
  int excl = si[tid] - comb;
  int gtB = excl >> 13;
  int eqB = excl & 0x1FFF;
  int* idxb = idxLoc + (size_t)b * idxB;
  int* gidxb = gIdx ? gIdx + (size_t)b * gIdxB : nullptr;
  const int* prevb = prevIdx ? prevIdx + (size_t)b * prevB : nullptr;
  for (int u = 0; u < ipt; u++) {
    int i = i0 + u;
    unsigned key = sk[i];
    bool g = key > tkey;
    bool e = (key == tkey);
    bool sel = g || (e && eqB < needEq);
    if (sel) {
      int pos = gtB + (eqB < needEq ? eqB : needEq);
      idxb[pos] = i;
      invb[i] = pos;
      int gi = prevb ? prevb[i] : i;
      if (gidxb) gidxb[pos] = gi;
      if (ginvb) ginvb[gi] = pos;
    }
    gtB += g ? 1 : 0;
    eqB += e ? 1 : 0;
  }
}

// ---------------- host side ----------------
static inline void launch_gemm(const float* in, const float* W, float* out, int M, int K, int C,
                               long inB, long outB, const int* map, int mapB, hipStream_t s,
                               const float* gateY = nullptr, long gyB = 0,
                               const float* invn = nullptr, int which = 0) {
  dim3 g(M / 64, BB), bl(32, 8);
  size_t lds = (size_t)(64 * C + 64 * 68) * 4;
  if (C == 64)
    gemm_kernel<2><<<g, bl, lds, s>>>(in, W, out, M, K, inB, outB, map, mapB, gateY, gyB, invn, which);
  else if (C == 96)
    gemm_kernel<3><<<g, bl, lds, s>>>(in, W, out, M, K, inB, outB, map, mapB, gateY, gyB, invn, which);
  else
    gemm_kernel<4><<<g, bl, lds, s>>>(in, W, out, M, K, inB, outB, map, mapB, gateY, gyB, invn, which);
}

static inline void launch_spmm(const int* ecol, const float* evals, const int* ennz,
                               const int* rowmap, int rowmapB, const int* colinv, int colinvB,
                               const float* Y, long yB, const float* bias, float* out, long outB,
                               int M, int C, int act, hipStream_t s,
                               const float* eps = nullptr, float* meanOut = nullptr,
                               float* lvOut = nullptr, float* zOut = nullptr,
                               const float* pvec = nullptr, float* yOut = nullptr, long yOutB = 0) {
  if (C == 128) {
    spmm_vec_kernel<128><<<dim3((M / 4) * BB), dim3(128), 0, s>>>(
        ecol, evals, ennz, rowmap, rowmapB, colinv, colinvB, Y, yB, bias, out, outB, act,
        eps, meanOut, lvOut, zOut, pvec, yOut, yOutB);
  } else if (C == 64) {
    spmm_vec_kernel<64><<<dim3((M / 8) * BB), dim3(128), 0, s>>>(
        ecol, evals, ennz, rowmap, rowmapB, colinv, colinvB, Y, yB, bias, out, outB, act,
        eps, meanOut, lvOut, zOut, pvec, yOut, yOutB);
  } else {
    spmm_kernel<<<dim3(M * BB), dim3(C), 0, s>>>(ecol, evals, ennz, rowmap, rowmapB, colinv,
                                                 colinvB, Y, yB, bias, out, outB, C, act);
  }
}

extern "C" void kernel_launch(void* const* d_in, const int* in_sizes, int n_in,
                              void* d_out, int out_size, void* d_ws, size_t ws_size,
                              hipStream_t stream) {
  const float* x = (const float*)d_in[0];
  const float* eps = (const float*)d_in[1];
  const float* A0 = (const float*)d_in[2];
  const float* W1 = (const float*)d_in[3];
  const float* b1 = (const float*)d_in[4];
  const float* p1 = (const float*)d_in[5];
  const float* W2 = (const float*)d_in[6];
  const float* b2 = (const float*)d_in[7];
  const float* p2 = (const float*)d_in[8];
  const float* Wlat = (const float*)d_in[9];
  const float* blat = (const float*)d_in[10];
  const float* Wd0 = (const float*)d_in[11];
  const float* bd0 = (const float*)d_in[12];
  const float* Wd1 = (const float*)d_in[13];
  const float* bd1 = (const float*)d_in[14];
  const float* Wd2 = (const float*)d_in[15];
  const float* bd2 = (const float*)d_in[16];
  const float* Wout = (const float*)d_in[17];
  const float* bout = (const float*)d_in[18];
  float* outp = (float*)d_out;
  float* meanOut = outp + (size_t)BB * 4096 * 64;
  float* logvarOut = meanOut + (size_t)BB * 1024 * 32;

  char* ws = (char*)d_ws;
  size_t off = 0;
  auto alloc = [&](size_t bytes) {
    void* p = ws + off;
    off = (off + bytes + 255) & ~(size_t)255;
    return p;
  };
  int* ell_col = (int*)alloc((size_t)NN * ELLCAP * 4);
  float* ell_val = (float*)alloc((size_t)NN * ELLCAP * 4);
  int* ell_nnz = (int*)alloc((size_t)NN * 4);
  float* invn = (float*)alloc(256);
  float* t0 = (float*)alloc((size_t)BB * 4096 * 128 * 4);
  float* t1 = (float*)alloc((size_t)BB * 4096 * 128 * 4);
  float* t2 = (float*)alloc((size_t)BB * 4096 * 128 * 4);
  float* y1 = (float*)alloc((size_t)BB * 4096 * 4);
  float* y2 = (float*)alloc((size_t)BB * 2048 * 4);
  int* idx1 = (int*)alloc((size_t)BB * 2048 * 4);
  int* inv1 = (int*)alloc((size_t)BB * 4096 * 4);
  int* idx2 = (int*)alloc((size_t)BB * 1024 * 4);
  int* inv2 = (int*)alloc((size_t)BB * 2048 * 4);
  int* gidx2 = (int*)alloc((size_t)BB * 1024 * 4);
  int* ginv2 = (int*)alloc((size_t)BB * 4096 * 4);
  float* zbuf = (float*)alloc((size_t)BB * 1024 * 32 * 4);

  // sparse structure + norms
  ell_build<<<dim3(NN), dim3(64), 0, stream>>>(A0, ell_col, ell_val, ell_nnz);
  pnorm_kernel<<<dim3(1), dim3(64), 0, stream>>>(p1, p2, invn);

  // ---- encoder level 0 ----
  launch_gemm(x, W1, t0, 4096, 64, 128, 4096l * 64, 4096l * 128, nullptr, 0, stream);
  launch_spmm(ell_col, ell_val, ell_nnz, nullptr, 0, nullptr, 0, t0, 4096l * 128, b1, t1,
              4096l * 128, 4096, 128, 1, stream, nullptr, nullptr, nullptr, nullptr,
              p1, y1, 4096);
  topk_kernel<<<dim3(BB), dim3(1024), 0, stream>>>(y1, 4096, 4096, 2048, nullptr, 0, idx1, 2048,
                                                   inv1, 4096, nullptr, 0, nullptr, 0);

  // ---- encoder level 1 (gather + gate fused into GEMM) ----
  launch_gemm(t1, W2, t0, 2048, 128, 64, 4096l * 128, 2048l * 64, idx1, 2048, stream,
              y1, 4096, invn, 0);
  launch_spmm(ell_col, ell_val, ell_nnz, idx1, 2048, inv1, 4096, t0, 2048l * 64, b2, t1,
              2048l * 64, 2048, 64, 1, stream, nullptr, nullptr, nullptr, nullptr,
              p2, y2, 2048);
  topk_kernel<<<dim3(BB), dim3(1024), 0, stream>>>(y2, 2048, 2048, 1024, idx1, 2048, idx2, 1024,
                                                   inv2, 2048, gidx2, 1024, ginv2, 4096);

  // ---- latent + reparameterize (gather+gate fused; writes mean/logvar to d_out, z to ws) ----
  launch_gemm(t1, Wlat, t0, 1024, 64, 64, 2048l * 64, 1024l * 64, idx2, 1024, stream,
              y2, 2048, invn, 1);
  launch_spmm(ell_col, ell_val, ell_nnz, gidx2, 1024, ginv2, 4096, t0, 1024l * 64, blat, nullptr,
              0, 1024, 64, 3, stream, eps, meanOut, logvarOut, zbuf);

  // ---- decoder ----
  launch_gemm(zbuf, Wd0, t0, 1024, 32, 64, 1024l * 32, 1024l * 64, nullptr, 0, stream);
  launch_spmm(ell_col, ell_val, ell_nnz, gidx2, 1024, ginv2, 4096, t0, 1024l * 64, bd0, t2,
              1024l * 64, 1024, 64, 1, stream);
  // unpool level2->level1 fused into scatter-GEMM (rows not in idx2 -> zero)
  launch_gemm(t2, Wd1, t0, 2048, 64, 96, 1024l * 64, 2048l * 96, inv2, 2048, stream);
  launch_spmm(ell_col, ell_val, ell_nnz, idx1, 2048, inv1, 4096, t0, 2048l * 96, bd1, t1,
              2048l * 96, 2048, 96, 1, stream);
  // unpool level1->level0 fused into scatter-GEMM
  launch_gemm(t1, Wd2, t0, 4096, 96, 128, 2048l * 96, 4096l * 128, inv1, 4096, stream);
  launch_spmm(ell_col, ell_val, ell_nnz, nullptr, 0, nullptr, 0, t0, 4096l * 128, bd2, t2,
              4096l * 128, 4096, 128, 1, stream);
  launch_gemm(t2, Wout, t0, 4096, 128, 64, 4096l * 128, 4096l * 64, nullptr, 0, stream);
  launch_spmm(ell_col, ell_val, ell_nnz, nullptr, 0, nullptr, 0, t0, 4096l * 64, bout, outp,
              4096l * 64, 4096, 64, 2, stream);
}

// Round 13
// 471.183 us; speedup vs baseline: 1.8294x; 1.0598x over previous
//
#include <hip/hip_runtime.h>
#include <hip/hip_bf16.h>

#define NN 4096
#define BB 8
#define LAT 32
#define ELLCAP 128

// ---------------- ELL build: extract sparse structure of A0 ----------------
__global__ void ell_build(const float* __restrict__ A, int* __restrict__ col,
                          float* __restrict__ val, int* __restrict__ nnz) {
  int row = blockIdx.x;
  int lane = threadIdx.x;  // 64
  const float* ar = A + (size_t)row * NN;
  int base = 0;
  for (int j0 = 0; j0 < NN; j0 += 64) {
    float a = ar[j0 + lane];
    unsigned long long m = __ballot(a != 0.0f);
    if (a != 0.0f) {
      int pos = base + __popcll(m & ((1ull << lane) - 1ull));
      if (pos < ELLCAP) {
        col[(size_t)row * ELLCAP + pos] = j0 + lane;
        val[(size_t)row * ELLCAP + pos] = a;
      }
    }
    base += __popcll(m);
  }
  if (lane == 0) nnz[row] = base < ELLCAP ? base : ELLCAP;
}

// ---------------- p-vector inverse norms ----------------
__global__ void pnorm_kernel(const float* __restrict__ p1, const float* __restrict__ p2,
                             float* __restrict__ invn) {
  int lane = threadIdx.x;  // 64
  float s1 = 0.f, s2 = 0.f;
  for (int i = lane; i < 128; i += 64) s1 += p1[i] * p1[i];
  { float v = p2[lane]; s2 = v * v; }
  for (int off = 32; off; off >>= 1) { s1 += __shfl_down(s1, off); s2 += __shfl_down(s2, off); }
  if (lane == 0) { invn[0] = rsqrtf(s1); invn[1] = rsqrtf(s2); }
}

// ---------------- dense GEMM v2: 32-row tiles, KT=32 (occupancy-oriented) ----
// grid (M/32, B), block (32,8). Each thread: acc[4][CT] (4 rows x CT cols).
// map: out-row -> src-row (-1 => zero row). gateY: row scaled by tanh(gateY[src]*invn[which]).
template <int CT>
__global__ __launch_bounds__(256) void gemm_kernel(
    const float* __restrict__ in, const float* __restrict__ W, float* __restrict__ out,
    int M, int K, long inB, long outB, const int* __restrict__ map, int mapB,
    const float* __restrict__ gateY, long gyB, const float* __restrict__ invn, int which) {
  const int C = CT * 32;
  const int KT = 32, LDI = KT + 4;
  extern __shared__ float lds[];
  float* Wl = lds;            // [KT][C]
  float* inT = lds + KT * C;  // [32][LDI]
  int b = blockIdx.y;
  const float* inb = in + (size_t)b * inB;
  float* outb = out + (size_t)b * outB;
  const int* mapb = map ? map + (size_t)b * mapB : nullptr;
  int tx = threadIdx.x, ty = threadIdx.y;
  int row0 = blockIdx.x * 32;
  float acc[4][CT];
#pragma unroll
  for (int i = 0; i < 4; i++)
#pragma unroll
    for (int j = 0; j < CT; j++) acc[i][j] = 0.f;
  for (int kt = 0; kt < K; kt += KT) {
    int kc = (K - kt < KT) ? (K - kt) : KT;
    for (int r = ty; r < kc; r += 8)
      for (int c = tx; c < C; c += 32) Wl[r * C + c] = W[(size_t)(kt + r) * C + c];
    for (int r = ty; r < 32; r += 8) {
      int grow = row0 + r;
      int src = grow;
      if (mapb) src = mapb[grow];
      if (src >= 0) {
        float gate = 1.f;
        if (gateY) gate = tanhf(gateY[(size_t)b * gyB + src] * invn[which]);
        const float* ib = inb + (size_t)src * K + kt;
        for (int k = tx; k < kc; k += 32) inT[r * LDI + k] = ib[k] * gate;
      } else {
        for (int k = tx; k < kc; k += 32) inT[r * LDI + k] = 0.f;
      }
    }
    __syncthreads();
    for (int k = 0; k < kc; k += 4) {
      float4 a[4];
#pragma unroll
      for (int i = 0; i < 4; i++) a[i] = *(const float4*)&inT[(ty + i * 8) * LDI + k];
#pragma unroll
      for (int kk = 0; kk < 4; kk++) {
#pragma unroll
        for (int j = 0; j < CT; j++) {
          float w = Wl[(k + kk) * C + tx + j * 32];
#pragma unroll
          for (int i = 0; i < 4; i++) {
            float av = ((const float*)&a[i])[kk];
            acc[i][j] = fmaf(av, w, acc[i][j]);
          }
        }
      }
    }
    __syncthreads();
  }
#pragma unroll
  for (int i = 0; i < 4; i++) {
    int grow = row0 + ty + i * 8;
#pragma unroll
    for (int j = 0; j < CT; j++) outb[(size_t)grow * C + tx + j * 32] = acc[i][j];
  }
}

// ---------------- SpMM v3: float4 lanes, XCD-pinned batch, 8-way MLP unroll ----
// C in {64,128}. L = C/4 lanes per row, R = 128/L rows per block.
// grid ((M/R)*8) 1D: rowblock = bid>>3, b = bid&7.
// act: 0=none 1=relu 2=softplus 3=VAE epilogue.
template <int C>
__global__ __launch_bounds__(128) void spmm_vec_kernel(
    const int* __restrict__ ecol, const float* __restrict__ evals, const int* __restrict__ ennz,
    const int* __restrict__ rowmap, int rowmapB,
    const int* __restrict__ colinv, int colinvB,
    const float* __restrict__ Y, long yB, const float* __restrict__ bias,
    float* __restrict__ out, long outB, int act,
    const float* __restrict__ eps, float* __restrict__ meanOut,
    float* __restrict__ logvarOut, float* __restrict__ zOut,
    const float* __restrict__ pvec, float* __restrict__ yOut, long yOutB) {
  constexpr int L = C / 4;
  constexpr int R = 128 / L;
  __shared__ int scol[R][ELLCAP];
  __shared__ float sval[R][ELLCAP];
  int bid = blockIdx.x;
  int rb = bid >> 3, b = bid & 7;
  int t = threadIdx.x;
  int rloc = t / L, lane = t % L;
  int row = rb * R + rloc;
  int grow = rowmap ? rowmap[(size_t)b * rowmapB + row] : row;
  int n = ennz[grow];
  const int* cp = ecol + (size_t)grow * ELLCAP;
  const float* vp = evals + (size_t)grow * ELLCAP;
  const int* ci = colinv ? colinv + (size_t)b * colinvB : nullptr;
  for (int e = lane; e < n; e += L) {
    int c = cp[e];
    int li = ci ? ci[c] : c;
    float w = vp[e];
    if (li < 0) { li = 0; w = 0.f; }
    scol[rloc][e] = li;
    sval[rloc][e] = w;
  }
  __syncthreads();
  const float* Yb = Y + (size_t)b * yB;
  float4 acc = {0.f, 0.f, 0.f, 0.f};
  int e = 0;
  for (; e + 8 <= n; e += 8) {
    float4 v[8];
    float w[8];
#pragma unroll
    for (int u = 0; u < 8; u++) {
      w[u] = sval[rloc][e + u];
      v[u] = *(const float4*)&Yb[(size_t)scol[rloc][e + u] * C + lane * 4];
    }
#pragma unroll
    for (int u = 0; u < 8; u++) {
      acc.x = fmaf(w[u], v[u].x, acc.x);
      acc.y = fmaf(w[u], v[u].y, acc.y);
      acc.z = fmaf(w[u], v[u].z, acc.z);
      acc.w = fmaf(w[u], v[u].w, acc.w);
    }
  }
  for (; e < n; e++) {
    float w = sval[rloc][e];
    float4 v = *(const float4*)&Yb[(size_t)scol[rloc][e] * C + lane * 4];
    acc.x = fmaf(w, v.x, acc.x);
    acc.y = fmaf(w, v.y, acc.y);
    acc.z = fmaf(w, v.z, acc.z);
    acc.w = fmaf(w, v.w, acc.w);
  }
  float4 bi = *(const float4*)&bias[lane * 4];
  acc.x += bi.x; acc.y += bi.y; acc.z += bi.z; acc.w += bi.w;
  if (act == 1) {
    acc.x = fmaxf(acc.x, 0.f); acc.y = fmaxf(acc.y, 0.f);
    acc.z = fmaxf(acc.z, 0.f); acc.w = fmaxf(acc.w, 0.f);
  } else if (act == 2) {
    acc.x = fmaxf(acc.x, 0.f) + log1pf(expf(-fabsf(acc.x)));
    acc.y = fmaxf(acc.y, 0.f) + log1pf(expf(-fabsf(acc.y)));
    acc.z = fmaxf(acc.z, 0.f) + log1pf(expf(-fabsf(acc.z)));
    acc.w = fmaxf(acc.w, 0.f) + log1pf(expf(-fabsf(acc.w)));
  } else if (act == 3) {
    // C=64: lanes 0..7 hold mean cols, lanes 8..15 hold logvar cols.
    int wl = t & 63;
    float4 lv;
    lv.x = __shfl(acc.x, wl + 8, 64);
    lv.y = __shfl(acc.y, wl + 8, 64);
    lv.z = __shfl(acc.z, wl + 8, 64);
    lv.w = __shfl(acc.w, wl + 8, 64);
    size_t o = ((size_t)b * 1024 + row) * LAT;
    if (lane < 8) {
      *(float4*)&meanOut[o + lane * 4] = acc;
      float4 ep = *(const float4*)&eps[o + lane * 4];
      float4 z;
      z.x = fmaf(expf(0.5f * lv.x), ep.x, acc.x);
      z.y = fmaf(expf(0.5f * lv.y), ep.y, acc.y);
      z.z = fmaf(expf(0.5f * lv.z), ep.z, acc.z);
      z.w = fmaf(expf(0.5f * lv.w), ep.w, acc.w);
      *(float4*)&zOut[o + lane * 4] = z;
    } else {
      *(float4*)&logvarOut[o + (lane - 8) * 4] = acc;
    }
    return;
  }
  *(float4*)&out[(size_t)b * outB + (size_t)row * C + lane * 4] = acc;
  if (yOut) {  // fused pooling-score dot, shfl tree within the row's L lanes
    float4 pv = *(const float4*)&pvec[lane * 4];
    float part = acc.x * pv.x + acc.y * pv.y + acc.z * pv.z + acc.w * pv.w;
#pragma unroll
    for (int off = L / 2; off > 0; off >>= 1) part += __shfl_down(part, off, 64);
    if (lane == 0) yOut[(size_t)b * yOutB + row] = part;
  }
}

// ---------------- SpMM scalar (C=96 path) ----------------
__global__ void spmm_kernel(
    const int* __restrict__ ecol, const float* __restrict__ evals, const int* __restrict__ ennz,
    const int* __restrict__ rowmap, int rowmapB,
    const int* __restrict__ colinv, int colinvB,
    const float* __restrict__ Y, long yB, const float* __restrict__ bias,
    float* __restrict__ out, long outB, int C, int act) {
  __shared__ int scol[ELLCAP];
  __shared__ float sval[ELLCAP];
  int bid = blockIdx.x;
  int row = bid >> 3, b = bid & 7;
  int t = threadIdx.x;
  int grow = rowmap ? rowmap[(size_t)b * rowmapB + row] : row;
  int n = ennz[grow];
  const int* cp = ecol + (size_t)grow * ELLCAP;
  const float* vp = evals + (size_t)grow * ELLCAP;
  const int* ci = colinv ? colinv + (size_t)b * colinvB : nullptr;
  for (int e = t; e < n; e += C) {
    int c = cp[e];
    int li = ci ? ci[c] : c;
    float w = vp[e];
    if (li < 0) { li = 0; w = 0.f; }
    scol[e] = li;
    sval[e] = w;
  }
  __syncthreads();
  const float* Yb = Y + (size_t)b * yB;
  float acc = 0.f;
  int e = 0;
  for (; e + 8 <= n; e += 8) {
    const float* ap[8];
    float w[8], pv[8];
#pragma unroll
    for (int u = 0; u < 8; u++) {
      ap[u] = Yb + (size_t)scol[e + u] * C + t;
      w[u] = sval[e + u];
    }
#pragma unroll
    for (int u = 0; u < 8; u++) pv[u] = *ap[u];
#pragma unroll
    for (int u = 0; u < 8; u++) acc = fmaf(w[u], pv[u], acc);
  }
  for (; e < n; e++) acc = fmaf(sval[e], Yb[(size_t)scol[e] * C + t], acc);
  acc += bias[t];
  if (act == 1) acc = fmaxf(acc, 0.f);
  out[(size_t)b * outB + (size_t)row * C + t] = acc;
}

// ---------------- top-k: radix select + ordered compaction ----------------
__global__ __launch_bounds__(1024) void topk_kernel(
    const float* __restrict__ yIn, int yB, int n, int k,
    const int* __restrict__ prevIdx, int prevB,
    int* __restrict__ idxLoc, int idxB,
    int* __restrict__ invLoc, int invB,
    int* __restrict__ gIdx, int gIdxB,
    int* __restrict__ gInv, int gInvB) {
  __shared__ unsigned int sk[4096];
  __shared__ unsigned int hist[256];
  __shared__ int si[1024];
  __shared__ int s_bin, s_cum;
  int b = blockIdx.x, tid = threadIdx.x;
  const float* y = yIn + (size_t)b * yB;
  for (int i = tid; i < n; i += 1024) {
    unsigned u = __float_as_uint(y[i]);
    sk[i] = (u & 0x80000000u) ? ~u : (u | 0x80000000u);
  }
  int* invb = invLoc + (size_t)b * invB;
  for (int i = tid; i < n; i += 1024) invb[i] = -1;
  int* ginvb = gInv ? gInv + (size_t)b * gInvB : nullptr;
  if (ginvb)
    for (int i = tid; i < NN; i += 1024) ginvb[i] = -1;
  __syncthreads();
  unsigned prefix = 0;
  int kneed = k, countGt = 0;
  for (int shift = 24; shift >= 0; shift -= 8) {
    if (tid < 256) hist[tid] = 0;
    __syncthreads();
    unsigned pmask = (shift == 24) ? 0u : (0xFFFFFFFFu << (shift + 8));
    for (int i = tid; i < n; i += 1024) {
      unsigned key = sk[i];
      if ((key & pmask) == prefix) atomicAdd(&hist[(key >> shift) & 255], 1u);
    }
    __syncthreads();
    if (tid < 256) si[tid] = (int)hist[tid];
    __syncthreads();
    for (int off = 1; off < 256; off <<= 1) {
      int v = 0;
      if (tid < 256) { v = si[tid]; if (tid + off < 256) v += si[tid + off]; }
      __syncthreads();
      if (tid < 256) si[tid] = v;
      __syncthreads();
    }
    if (tid < 256) {
      int cumAbove = (tid < 255) ? si[tid + 1] : 0;
      if (cumAbove < kneed && kneed <= cumAbove + (int)hist[tid]) {
        s_bin = tid;
        s_cum = cumAbove;
      }
    }
    __syncthreads();
    int bin = s_bin, cumAbove = s_cum;
    countGt += cumAbove;
    kneed -= cumAbove;
    prefix |= ((unsigned)bin << shift);
    __syncthreads();
  }
  unsigned tkey = prefix;
  int needEq = k - countGt;
  int ipt = n >> 10;
  int i0 = tid * ipt;
  int locGt = 0, locEq = 0;
  for (int u = 0; u < ipt; u++) {
    unsigned key = sk[i0 + u];
    locGt += (key > tkey) ? 1 : 0;
    locEq += (key == tkey) ? 1 : 0;
  }
  int comb = (locGt << 13) | locEq;
  si[tid] = comb;
  __syncthreads();
  for (int off = 1; off < 1024; off <<= 1) {
    int vv = si[tid];
    int add = (tid >= off) ? si[tid - off] : 0;
    __syncthreads();
    si[tid] = vv + add;
    __syncthreads();
  }
  int excl = si[tid] - comb;
  int gtB = excl >> 13;
  int eqB = excl & 0x1FFF;
  int* idxb = idxLoc + (size_t)b * idxB;
  int* gidxb = gIdx ? gIdx + (size_t)b * gIdxB : nullptr;
  const int* prevb = prevIdx ? prevIdx + (size_t)b * prevB : nullptr;
  for (int u = 0; u < ipt; u++) {
    int i = i0 + u;
    unsigned key = sk[i];
    bool g = key > tkey;
    bool e = (key == tkey);
    bool sel = g || (e && eqB < needEq);
    if (sel) {
      int pos = gtB + (eqB < needEq ? eqB : needEq);
      idxb[pos] = i;
      invb[i] = pos;
      int gi = prevb ? prevb[i] : i;
      if (gidxb) gidxb[pos] = gi;
      if (ginvb) ginvb[gi] = pos;
    }
    gtB += g ? 1 : 0;
    eqB += e ? 1 : 0;
  }
}

// ---------------- host side ----------------
static inline void launch_gemm(const float* in, const float* W, float* out, int M, int K, int C,
                               long inB, long outB, const int* map, int mapB, hipStream_t s,
                               const float* gateY = nullptr, long gyB = 0,
                               const float* invn = nullptr, int which = 0) {
  dim3 g(M / 32, BB), bl(32, 8);
  size_t lds = (size_t)(32 * C + 32 * 36) * 4;
  if (C == 64)
    gemm_kernel<2><<<g, bl, lds, s>>>(in, W, out, M, K, inB, outB, map, mapB, gateY, gyB, invn, which);
  else if (C == 96)
    gemm_kernel<3><<<g, bl, lds, s>>>(in, W, out, M, K, inB, outB, map, mapB, gateY, gyB, invn, which);
  else
    gemm_kernel<4><<<g, bl, lds, s>>>(in, W, out, M, K, inB, outB, map, mapB, gateY, gyB, invn, which);
}

static inline void launch_spmm(const int* ecol, const float* evals, const int* ennz,
                               const int* rowmap, int rowmapB, const int* colinv, int colinvB,
                               const float* Y, long yB, const float* bias, float* out, long outB,
                               int M, int C, int act, hipStream_t s,
                               const float* eps = nullptr, float* meanOut = nullptr,
                               float* lvOut = nullptr, float* zOut = nullptr,
                               const float* pvec = nullptr, float* yOut = nullptr, long yOutB = 0) {
  if (C == 128) {
    spmm_vec_kernel<128><<<dim3((M / 4) * BB), dim3(128), 0, s>>>(
        ecol, evals, ennz, rowmap, rowmapB, colinv, colinvB, Y, yB, bias, out, outB, act,
        eps, meanOut, lvOut, zOut, pvec, yOut, yOutB);
  } else if (C == 64) {
    spmm_vec_kernel<64><<<dim3((M / 8) * BB), dim3(128), 0, s>>>(
        ecol, evals, ennz, rowmap, rowmapB, colinv, colinvB, Y, yB, bias, out, outB, act,
        eps, meanOut, lvOut, zOut, pvec, yOut, yOutB);
  } else {
    spmm_kernel<<<dim3(M * BB), dim3(C), 0, s>>>(ecol, evals, ennz, rowmap, rowmapB, colinv,
                                                 colinvB, Y, yB, bias, out, outB, C, act);
  }
}

extern "C" void kernel_launch(void* const* d_in, const int* in_sizes, int n_in,
                              void* d_out, int out_size, void* d_ws, size_t ws_size,
                              hipStream_t stream) {
  const float* x = (const float*)d_in[0];
  const float* eps = (const float*)d_in[1];
  const float* A0 = (const float*)d_in[2];
  const float* W1 = (const float*)d_in[3];
  const float* b1 = (const float*)d_in[4];
  const float* p1 = (const float*)d_in[5];
  const float* W2 = (const float*)d_in[6];
  const float* b2 = (const float*)d_in[7];
  const float* p2 = (const float*)d_in[8];
  const float* Wlat = (const float*)d_in[9];
  const float* blat = (const float*)d_in[10];
  const float* Wd0 = (const float*)d_in[11];
  const float* bd0 = (const float*)d_in[12];
  const float* Wd1 = (const float*)d_in[13];
  const float* bd1 = (const float*)d_in[14];
  const float* Wd2 = (const float*)d_in[15];
  const float* bd2 = (const float*)d_in[16];
  const float* Wout = (const float*)d_in[17];
  const float* bout = (const float*)d_in[18];
  float* outp = (float*)d_out;
  float* meanOut = outp + (size_t)BB * 4096 * 64;
  float* logvarOut = meanOut + (size_t)BB * 1024 * 32;

  char* ws = (char*)d_ws;
  size_t off = 0;
  auto alloc = [&](size_t bytes) {
    void* p = ws + off;
    off = (off + bytes + 255) & ~(size_t)255;
    return p;
  };
  int* ell_col = (int*)alloc((size_t)NN * ELLCAP * 4);
  float* ell_val = (float*)alloc((size_t)NN * ELLCAP * 4);
  int* ell_nnz = (int*)alloc((size_t)NN * 4);
  float* invn = (float*)alloc(256);
  float* t0 = (float*)alloc((size_t)BB * 4096 * 128 * 4);
  float* t1 = (float*)alloc((size_t)BB * 4096 * 128 * 4);
  float* t2 = (float*)alloc((size_t)BB * 4096 * 128 * 4);
  float* y1 = (float*)alloc((size_t)BB * 4096 * 4);
  float* y2 = (float*)alloc((size_t)BB * 2048 * 4);
  int* idx1 = (int*)alloc((size_t)BB * 2048 * 4);
  int* inv1 = (int*)alloc((size_t)BB * 4096 * 4);
  int* idx2 = (int*)alloc((size_t)BB * 1024 * 4);
  int* inv2 = (int*)alloc((size_t)BB * 2048 * 4);
  int* gidx2 = (int*)alloc((size_t)BB * 1024 * 4);
  int* ginv2 = (int*)alloc((size_t)BB * 4096 * 4);
  float* zbuf = (float*)alloc((size_t)BB * 1024 * 32 * 4);

  // sparse structure + norms
  ell_build<<<dim3(NN), dim3(64), 0, stream>>>(A0, ell_col, ell_val, ell_nnz);
  pnorm_kernel<<<dim3(1), dim3(64), 0, stream>>>(p1, p2, invn);

  // ---- encoder level 0 ----
  launch_gemm(x, W1, t0, 4096, 64, 128, 4096l * 64, 4096l * 128, nullptr, 0, stream);
  launch_spmm(ell_col, ell_val, ell_nnz, nullptr, 0, nullptr, 0, t0, 4096l * 128, b1, t1,
              4096l * 128, 4096, 128, 1, stream, nullptr, nullptr, nullptr, nullptr,
              p1, y1, 4096);
  topk_kernel<<<dim3(BB), dim3(1024), 0, stream>>>(y1, 4096, 4096, 2048, nullptr, 0, idx1, 2048,
                                                   inv1, 4096, nullptr, 0, nullptr, 0);

  // ---- encoder level 1 (gather + gate fused into GEMM) ----
  launch_gemm(t1, W2, t0, 2048, 128, 64, 4096l * 128, 2048l * 64, idx1, 2048, stream,
              y1, 4096, invn, 0);
  launch_spmm(ell_col, ell_val, ell_nnz, idx1, 2048, inv1, 4096, t0, 2048l * 64, b2, t1,
              2048l * 64, 2048, 64, 1, stream, nullptr, nullptr, nullptr, nullptr,
              p2, y2, 2048);
  topk_kernel<<<dim3(BB), dim3(1024), 0, stream>>>(y2, 2048, 2048, 1024, idx1, 2048, idx2, 1024,
                                                   inv2, 2048, gidx2, 1024, ginv2, 4096);

  // ---- latent + reparameterize (gather+gate fused; writes mean/logvar to d_out, z to ws) ----
  launch_gemm(t1, Wlat, t0, 1024, 64, 64, 2048l * 64, 1024l * 64, idx2, 1024, stream,
              y2, 2048, invn, 1);
  launch_spmm(ell_col, ell_val, ell_nnz, gidx2, 1024, ginv2, 4096, t0, 1024l * 64, blat, nullptr,
              0, 1024, 64, 3, stream, eps, meanOut, logvarOut, zbuf);

  // ---- decoder ----
  launch_gemm(zbuf, Wd0, t0, 1024, 32, 64, 1024l * 32, 1024l * 64, nullptr, 0, stream);
  launch_spmm(ell_col, ell_val, ell_nnz, gidx2, 1024, ginv2, 4096, t0, 1024l * 64, bd0, t2,
              1024l * 64, 1024, 64, 1, stream);
  // unpool level2->level1 fused into scatter-GEMM (rows not in idx2 -> zero)
  launch_gemm(t2, Wd1, t0, 2048, 64, 96, 1024l * 64, 2048l * 96, inv2, 2048, stream);
  launch_spmm(ell_col, ell_val, ell_nnz, idx1, 2048, inv1, 4096, t0, 2048l * 96, bd1, t1,
              2048l * 96, 2048, 96, 1, stream);
  // unpool level1->level0 fused into scatter-GEMM
  launch_gemm(t1, Wd2, t0, 4096, 96, 128, 2048l * 96, 4096l * 128, inv1, 4096, stream);
  launch_spmm(ell_col, ell_val, ell_nnz, nullptr, 0, nullptr, 0, t0, 4096l * 128, bd2, t2,
              4096l * 128, 4096, 128, 1, stream);
  launch_gemm(t2, Wout, t0, 4096, 128, 64, 4096l * 128, 4096l * 64, nullptr, 0, stream);
  launch_spmm(ell_col, ell_val, ell_nnz, nullptr, 0, nullptr, 0, t0, 4096l * 64, bout, outp,
              4096l * 64, 4096, 64, 2, stream);
}

// Round 14
// 452.054 us; speedup vs baseline: 1.9068x; 1.0423x over previous
//
#include <hip/hip_runtime.h>
#include <hip/hip_bf16.h>

#define NN 4096
#define BB 8
#define LAT 32
#define ELLCAP 128

// ---------------- ELL build v2: float4 loads + wave-prefix compaction ----------------
// 4 rows per 256-thread block (one wave per row). 16 x 1KB loads per row.
__global__ __launch_bounds__(256) void ell_build(const float* __restrict__ A,
                                                 int* __restrict__ col,
                                                 float* __restrict__ val,
                                                 int* __restrict__ nnz) {
  int w = threadIdx.x >> 6;  // wave id 0..3
  int lane = threadIdx.x & 63;
  int row = blockIdx.x * 4 + w;
  const float* ar = A + (size_t)row * NN;
  int base = 0;
  for (int i = 0; i < NN; i += 256) {
    float4 a = *(const float4*)&ar[i + lane * 4];
    int cnt = (a.x != 0.f) + (a.y != 0.f) + (a.z != 0.f) + (a.w != 0.f);
    int x = cnt;
#pragma unroll
    for (int off = 1; off < 64; off <<= 1) {
      int y = __shfl_up(x, off, 64);
      if (lane >= off) x += y;
    }
    int total = __shfl(x, 63, 64);
    int p = base + x - cnt;  // exclusive prefix within row
    float av[4] = {a.x, a.y, a.z, a.w};
#pragma unroll
    for (int u = 0; u < 4; u++) {
      if (av[u] != 0.f) {
        if (p < ELLCAP) {
          col[(size_t)row * ELLCAP + p] = i + lane * 4 + u;
          val[(size_t)row * ELLCAP + p] = av[u];
        }
        p++;
      }
    }
    base += total;
  }
  if (lane == 0) nnz[row] = base < ELLCAP ? base : ELLCAP;
}

// ---------------- p-vector inverse norms ----------------
__global__ void pnorm_kernel(const float* __restrict__ p1, const float* __restrict__ p2,
                             float* __restrict__ invn) {
  int lane = threadIdx.x;  // 64
  float s1 = 0.f, s2 = 0.f;
  for (int i = lane; i < 128; i += 64) s1 += p1[i] * p1[i];
  { float v = p2[lane]; s2 = v * v; }
  for (int off = 32; off; off >>= 1) { s1 += __shfl_down(s1, off); s2 += __shfl_down(s2, off); }
  if (lane == 0) { invn[0] = rsqrtf(s1); invn[1] = rsqrtf(s2); }
}

// ---------------- dense GEMM v2: 32-row tiles, KT=32 (occupancy-oriented) ----------------
// grid (M/32, B), block (32,8). Each thread: acc[4][CT] (4 rows x CT cols).
// map: out-row -> src-row (-1 => zero row). gateY: row scaled by tanh(gateY[src]*invn[which]).
template <int CT>
__global__ __launch_bounds__(256) void gemm_kernel(
    const float* __restrict__ in, const float* __restrict__ W, float* __restrict__ out,
    int M, int K, long inB, long outB, const int* __restrict__ map, int mapB,
    const float* __restrict__ gateY, long gyB, const float* __restrict__ invn, int which) {
  const int C = CT * 32;
  const int KT = 32, LDI = KT + 4;
  extern __shared__ float lds[];
  float* Wl = lds;            // [KT][C]
  float* inT = lds + KT * C;  // [32][LDI]
  int b = blockIdx.y;
  const float* inb = in + (size_t)b * inB;
  float* outb = out + (size_t)b * outB;
  const int* mapb = map ? map + (size_t)b * mapB : nullptr;
  int tx = threadIdx.x, ty = threadIdx.y;
  int row0 = blockIdx.x * 32;
  float acc[4][CT];
#pragma unroll
  for (int i = 0; i < 4; i++)
#pragma unroll
    for (int j = 0; j < CT; j++) acc[i][j] = 0.f;
  for (int kt = 0; kt < K; kt += KT) {
    int kc = (K - kt < KT) ? (K - kt) : KT;
    for (int r = ty; r < kc; r += 8)
      for (int c = tx; c < C; c += 32) Wl[r * C + c] = W[(size_t)(kt + r) * C + c];
    for (int r = ty; r < 32; r += 8) {
      int grow = row0 + r;
      int src = grow;
      if (mapb) src = mapb[grow];
      if (src >= 0) {
        float gate = 1.f;
        if (gateY) gate = tanhf(gateY[(size_t)b * gyB + src] * invn[which]);
        const float* ib = inb + (size_t)src * K + kt;
        for (int k = tx; k < kc; k += 32) inT[r * LDI + k] = ib[k] * gate;
      } else {
        for (int k = tx; k < kc; k += 32) inT[r * LDI + k] = 0.f;
      }
    }
    __syncthreads();
    for (int k = 0; k < kc; k += 4) {
      float4 a[4];
#pragma unroll
      for (int i = 0; i < 4; i++) a[i] = *(const float4*)&inT[(ty + i * 8) * LDI + k];
#pragma unroll
      for (int kk = 0; kk < 4; kk++) {
#pragma unroll
        for (int j = 0; j < CT; j++) {
          float w = Wl[(k + kk) * C + tx + j * 32];
#pragma unroll
          for (int i = 0; i < 4; i++) {
            float av = ((const float*)&a[i])[kk];
            acc[i][j] = fmaf(av, w, acc[i][j]);
          }
        }
      }
    }
    __syncthreads();
  }
#pragma unroll
  for (int i = 0; i < 4; i++) {
    int grow = row0 + ty + i * 8;
#pragma unroll
    for (int j = 0; j < CT; j++) outb[(size_t)grow * C + tx + j * 32] = acc[i][j];
  }
}

// ---------------- SpMM v3: float4 lanes, XCD-pinned batch, 8-way MLP unroll ----------------
// C in {64,128}. L = C/4 lanes per row, R = 128/L rows per block.
// grid ((M/R)*8) 1D: rowblock = bid>>3, b = bid&7.
// act: 0=none 1=relu 2=softplus 3=VAE epilogue.
template <int C>
__global__ __launch_bounds__(128) void spmm_vec_kernel(
    const int* __restrict__ ecol, const float* __restrict__ evals, const int* __restrict__ ennz,
    const int* __restrict__ rowmap, int rowmapB,
    const int* __restrict__ colinv, int colinvB,
    const float* __restrict__ Y, long yB, const float* __restrict__ bias,
    float* __restrict__ out, long outB, int act,
    const float* __restrict__ eps, float* __restrict__ meanOut,
    float* __restrict__ logvarOut, float* __restrict__ zOut,
    const float* __restrict__ pvec, float* __restrict__ yOut, long yOutB) {
  constexpr int L = C / 4;
  constexpr int R = 128 / L;
  __shared__ int scol[R][ELLCAP];
  __shared__ float sval[R][ELLCAP];
  int bid = blockIdx.x;
  int rb = bid >> 3, b = bid & 7;
  int t = threadIdx.x;
  int rloc = t / L, lane = t % L;
  int row = rb * R + rloc;
  int grow = rowmap ? rowmap[(size_t)b * rowmapB + row] : row;
  int n = ennz[grow];
  const int* cp = ecol + (size_t)grow * ELLCAP;
  const float* vp = evals + (size_t)grow * ELLCAP;
  const int* ci = colinv ? colinv + (size_t)b * colinvB : nullptr;
  for (int e = lane; e < n; e += L) {
    int c = cp[e];
    int li = ci ? ci[c] : c;
    float w = vp[e];
    if (li < 0) { li = 0; w = 0.f; }
    scol[rloc][e] = li;
    sval[rloc][e] = w;
  }
  __syncthreads();
  const float* Yb = Y + (size_t)b * yB;
  float4 acc = {0.f, 0.f, 0.f, 0.f};
  int e = 0;
  for (; e + 8 <= n; e += 8) {
    float4 v[8];
    float w[8];
#pragma unroll
    for (int u = 0; u < 8; u++) {
      w[u] = sval[rloc][e + u];
      v[u] = *(const float4*)&Yb[(size_t)scol[rloc][e + u] * C + lane * 4];
    }
#pragma unroll
    for (int u = 0; u < 8; u++) {
      acc.x = fmaf(w[u], v[u].x, acc.x);
      acc.y = fmaf(w[u], v[u].y, acc.y);
      acc.z = fmaf(w[u], v[u].z, acc.z);
      acc.w = fmaf(w[u], v[u].w, acc.w);
    }
  }
  for (; e < n; e++) {
    float w = sval[rloc][e];
    float4 v = *(const float4*)&Yb[(size_t)scol[rloc][e] * C + lane * 4];
    acc.x = fmaf(w, v.x, acc.x);
    acc.y = fmaf(w, v.y, acc.y);
    acc.z = fmaf(w, v.z, acc.z);
    acc.w = fmaf(w, v.w, acc.w);
  }
  float4 bi = *(const float4*)&bias[lane * 4];
  acc.x += bi.x; acc.y += bi.y; acc.z += bi.z; acc.w += bi.w;
  if (act == 1) {
    acc.x = fmaxf(acc.x, 0.f); acc.y = fmaxf(acc.y, 0.f);
    acc.z = fmaxf(acc.z, 0.f); acc.w = fmaxf(acc.w, 0.f);
  } else if (act == 2) {
    acc.x = fmaxf(acc.x, 0.f) + log1pf(expf(-fabsf(acc.x)));
    acc.y = fmaxf(acc.y, 0.f) + log1pf(expf(-fabsf(acc.y)));
    acc.z = fmaxf(acc.z, 0.f) + log1pf(expf(-fabsf(acc.z)));
    acc.w = fmaxf(acc.w, 0.f) + log1pf(expf(-fabsf(acc.w)));
  } else if (act == 3) {
    // C=64: lanes 0..7 hold mean cols, lanes 8..15 hold logvar cols.
    int wl = t & 63;
    float4 lv;
    lv.x = __shfl(acc.x, wl + 8, 64);
    lv.y = __shfl(acc.y, wl + 8, 64);
    lv.z = __shfl(acc.z, wl + 8, 64);
    lv.w = __shfl(acc.w, wl + 8, 64);
    size_t o = ((size_t)b * 1024 + row) * LAT;
    if (lane < 8) {
      *(float4*)&meanOut[o + lane * 4] = acc;
      float4 ep = *(const float4*)&eps[o + lane * 4];
      float4 z;
      z.x = fmaf(expf(0.5f * lv.x), ep.x, acc.x);
      z.y = fmaf(expf(0.5f * lv.y), ep.y, acc.y);
      z.z = fmaf(expf(0.5f * lv.z), ep.z, acc.z);
      z.w = fmaf(expf(0.5f * lv.w), ep.w, acc.w);
      *(float4*)&zOut[o + lane * 4] = z;
    } else {
      *(float4*)&logvarOut[o + (lane - 8) * 4] = acc;
    }
    return;
  }
  *(float4*)&out[(size_t)b * outB + (size_t)row * C + lane * 4] = acc;
  if (yOut) {  // fused pooling-score dot, shfl tree within the row's L lanes
    float4 pv = *(const float4*)&pvec[lane * 4];
    float part = acc.x * pv.x + acc.y * pv.y + acc.z * pv.z + acc.w * pv.w;
#pragma unroll
    for (int off = L / 2; off > 0; off >>= 1) part += __shfl_down(part, off, 64);
    if (lane == 0) yOut[(size_t)b * yOutB + row] = part;
  }
}

// ---------------- SpMM scalar (C=96 path) ----------------
__global__ void spmm_kernel(
    const int* __restrict__ ecol, const float* __restrict__ evals, const int* __restrict__ ennz,
    const int* __restrict__ rowmap, int rowmapB,
    const int* __restrict__ colinv, int colinvB,
    const float* __restrict__ Y, long yB, const float* __restrict__ bias,
    float* __restrict__ out, long outB, int C, int act) {
  __shared__ int scol[ELLCAP];
  __shared__ float sval[ELLCAP];
  int bid = blockIdx.x;
  int row = bid >> 3, b = bid & 7;
  int t = threadIdx.x;
  int grow = rowmap ? rowmap[(size_t)b * rowmapB + row] : row;
  int n = ennz[grow];
  const int* cp = ecol + (size_t)grow * ELLCAP;
  const float* vp = evals + (size_t)grow * ELLCAP;
  const int* ci = colinv ? colinv + (size_t)b * colinvB : nullptr;
  for (int e = t; e < n; e += C) {
    int c = cp[e];
    int li = ci ? ci[c] : c;
    float w = vp[e];
    if (li < 0) { li = 0; w = 0.f; }
    scol[e] = li;
    sval[e] = w;
  }
  __syncthreads();
  const float* Yb = Y + (size_t)b * yB;
  float acc = 0.f;
  int e = 0;
  for (; e + 8 <= n; e += 8) {
    const float* ap[8];
    float w[8], pv[8];
#pragma unroll
    for (int u = 0; u < 8; u++) {
      ap[u] = Yb + (size_t)scol[e + u] * C + t;
      w[u] = sval[e + u];
    }
#pragma unroll
    for (int u = 0; u < 8; u++) pv[u] = *ap[u];
#pragma unroll
    for (int u = 0; u < 8; u++) acc = fmaf(w[u], pv[u], acc);
  }
  for (; e < n; e++) acc = fmaf(sval[e], Yb[(size_t)scol[e] * C + t], acc);
  acc += bias[t];
  if (act == 1) acc = fmaxf(acc, 0.f);
  out[(size_t)b * outB + (size_t)row * C + t] = acc;
}

// ---------------- top-k: radix select + ordered compaction ----------------
__global__ __launch_bounds__(1024) void topk_kernel(
    const float* __restrict__ yIn, int yB, int n, int k,
    const int* __restrict__ prevIdx, int prevB,
    int* __restrict__ idxLoc, int idxB,
    int* __restrict__ invLoc, int invB,
    int* __restrict__ gIdx, int gIdxB,
    int* __restrict__ gInv, int gInvB) {
  __shared__ unsigned int sk[4096];
  __shared__ unsigned int hist[256];
  __shared__ int si[1024];
  __shared__ int s_bin, s_cum;
  int b = blockIdx.x, tid = threadIdx.x;
  const float* y = yIn + (size_t)b * yB;
  for (int i = tid; i < n; i += 1024) {
    unsigned u = __float_as_uint(y[i]);
    sk[i] = (u & 0x80000000u) ? ~u : (u | 0x80000000u);
  }
  int* invb = invLoc + (size_t)b * invB;
  for (int i = tid; i < n; i += 1024) invb[i] = -1;
  int* ginvb = gInv ? gInv + (size_t)b * gInvB : nullptr;
  if (ginvb)
    for (int i = tid; i < NN; i += 1024) ginvb[i] = -1;
  __syncthreads();
  unsigned prefix = 0;
  int kneed = k, countGt = 0;
  for (int shift = 24; shift >= 0; shift -= 8) {
    if (tid < 256) hist[tid] = 0;
    __syncthreads();
    unsigned pmask = (shift == 24) ? 0u : (0xFFFFFFFFu << (shift + 8));
    for (int i = tid; i < n; i += 1024) {
      unsigned key = sk[i];
      if ((key & pmask) == prefix) atomicAdd(&hist[(key >> shift) & 255], 1u);
    }
    __syncthreads();
    if (tid < 256) si[tid] = (int)hist[tid];
    __syncthreads();
    for (int off = 1; off < 256; off <<= 1) {
      int v = 0;
      if (tid < 256) { v = si[tid]; if (tid + off < 256) v += si[tid + off]; }
      __syncthreads();
      if (tid < 256) si[tid] = v;
      __syncthreads();
    }
    if (tid < 256) {
      int cumAbove = (tid < 255) ? si[tid + 1] : 0;
      if (cumAbove < kneed && kneed <= cumAbove + (int)hist[tid]) {
        s_bin = tid;
        s_cum = cumAbove;
      }
    }
    __syncthreads();
    int bin = s_bin, cumAbove = s_cum;
    countGt += cumAbove;
    kneed -= cumAbove;
    prefix |= ((unsigned)bin << shift);
    __syncthreads();
  }
  unsigned tkey = prefix;
  int needEq = k - countGt;
  int ipt = n >> 10;
  int i0 = tid * ipt;
  int locGt = 0, locEq = 0;
  for (int u = 0; u < ipt; u++) {
    unsigned key = sk[i0 + u];
    locGt += (key > tkey) ? 1 : 0;
    locEq += (key == tkey) ? 1 : 0;
  }
  int comb = (locGt << 13) | locEq;
  si[tid] = comb;
  __syncthreads();
  for (int off = 1; off < 1024; off <<= 1) {
    int vv = si[tid];
    int add = (tid >= off) ? si[tid - off] : 0;
    __syncthreads();
    si[tid] = vv + add;
    __syncthreads();
  }
  int excl = si[tid] - comb;
  int gtB = excl >> 13;
  int eqB = excl & 0x1FFF;
  int* idxb = idxLoc + (size_t)b * idxB;
  int* gidxb = gIdx ? gIdx + (size_t)b * gIdxB : nullptr;
  const int* prevb = prevIdx ? prevIdx + (size_t)b * prevB : nullptr;
  for (int u = 0; u < ipt; u++) {
    int i = i0 + u;
    unsigned key = sk[i];
    bool g = key > tkey;
    bool e = (key == tkey);
    bool sel = g || (e && eqB < needEq);
    if (sel) {
      int pos = gtB + (eqB < needEq ? eqB : needEq);
      idxb[pos] = i;
      invb[i] = pos;
      int gi = prevb ? prevb[i] : i;
      if (gidxb) gidxb[pos] = gi;
      if (ginvb) ginvb[gi] = pos;
    }
    gtB += g ? 1 : 0;
    eqB += e ? 1 : 0;
  }
}

// ---------------- host side ----------------
static inline void launch_gemm(const float* in, const float* W, float* out, int M, int K, int C,
                               long inB, long outB, const int* map, int mapB, hipStream_t s,
                               const float* gateY = nullptr, long gyB = 0,
                               const float* invn = nullptr, int which = 0) {
  dim3 g(M / 32, BB), bl(32, 8);
  size_t lds = (size_t)(32 * C + 32 * 36) * 4;
  if (C == 64)
    gemm_kernel<2><<<g, bl, lds, s>>>(in, W, out, M, K, inB, outB, map, mapB, gateY, gyB, invn, which);
  else if (C == 96)
    gemm_kernel<3><<<g, bl, lds, s>>>(in, W, out, M, K, inB, outB, map, mapB, gateY, gyB, invn, which);
  else
    gemm_kernel<4><<<g, bl, lds, s>>>(in, W, out, M, K, inB, outB, map, mapB, gateY, gyB, invn, which);
}

static inline void launch_spmm(const int* ecol, const float* evals, const int* ennz,
                               const int* rowmap, int rowmapB, const int* colinv, int colinvB,
                               const float* Y, long yB, const float* bias, float* out, long outB,
                               int M, int C, int act, hipStream_t s,
                               const float* eps = nullptr, float* meanOut = nullptr,
                               float* lvOut = nullptr, float* zOut = nullptr,
                               const float* pvec = nullptr, float* yOut = nullptr, long yOutB = 0) {
  if (C == 128) {
    spmm_vec_kernel<128><<<dim3((M / 4) * BB), dim3(128), 0, s>>>(
        ecol, evals, ennz, rowmap, rowmapB, colinv, colinvB, Y, yB, bias, out, outB, act,
        eps, meanOut, lvOut, zOut, pvec, yOut, yOutB);
  } else if (C == 64) {
    spmm_vec_kernel<64><<<dim3((M / 8) * BB), dim3(128), 0, s>>>(
        ecol, evals, ennz, rowmap, rowmapB, colinv, colinvB, Y, yB, bias, out, outB, act,
        eps, meanOut, lvOut, zOut, pvec, yOut, yOutB);
  } else {
    spmm_kernel<<<dim3(M * BB), dim3(C), 0, s>>>(ecol, evals, ennz, rowmap, rowmapB, colinv,
                                                 colinvB, Y, yB, bias, out, outB, C, act);
  }
}

extern "C" void kernel_launch(void* const* d_in, const int* in_sizes, int n_in,
                              void* d_out, int out_size, void* d_ws, size_t ws_size,
                              hipStream_t stream) {
  const float* x = (const float*)d_in[0];
  const float* eps = (const float*)d_in[1];
  const float* A0 = (const float*)d_in[2];
  const float* W1 = (const float*)d_in[3];
  const float* b1 = (const float*)d_in[4];
  const float* p1 = (const float*)d_in[5];
  const float* W2 = (const float*)d_in[6];
  const float* b2 = (const float*)d_in[7];
  const float* p2 = (const float*)d_in[8];
  const float* Wlat = (const float*)d_in[9];
  const float* blat = (const float*)d_in[10];
  const float* Wd0 = (const float*)d_in[11];
  const float* bd0 = (const float*)d_in[12];
  const float* Wd1 = (const float*)d_in[13];
  const float* bd1 = (const float*)d_in[14];
  const float* Wd2 = (const float*)d_in[15];
  const float* bd2 = (const float*)d_in[16];
  const float* Wout = (const float*)d_in[17];
  const float* bout = (const float*)d_in[18];
  float* outp = (float*)d_out;
  float* meanOut = outp + (size_t)BB * 4096 * 64;
  float* logvarOut = meanOut + (size_t)BB * 1024 * 32;

  char* ws = (char*)d_ws;
  size_t off = 0;
  auto alloc = [&](size_t bytes) {
    void* p = ws + off;
    off = (off + bytes + 255) & ~(size_t)255;
    return p;
  };
  int* ell_col = (int*)alloc((size_t)NN * ELLCAP * 4);
  float* ell_val = (float*)alloc((size_t)NN * ELLCAP * 4);
  int* ell_nnz = (int*)alloc((size_t)NN * 4);
  float* invn = (float*)alloc(256);
  float* t0 = (float*)alloc((size_t)BB * 4096 * 128 * 4);
  float* t1 = (float*)alloc((size_t)BB * 4096 * 128 * 4);
  float* t2 = (float*)alloc((size_t)BB * 4096 * 128 * 4);
  float* y1 = (float*)alloc((size_t)BB * 4096 * 4);
  float* y2 = (float*)alloc((size_t)BB * 2048 * 4);
  int* idx1 = (int*)alloc((size_t)BB * 2048 * 4);
  int* inv1 = (int*)alloc((size_t)BB * 4096 * 4);
  int* idx2 = (int*)alloc((size_t)BB * 1024 * 4);
  int* inv2 = (int*)alloc((size_t)BB * 2048 * 4);
  int* gidx2 = (int*)alloc((size_t)BB * 1024 * 4);
  int* ginv2 = (int*)alloc((size_t)BB * 4096 * 4);
  float* zbuf = (float*)alloc((size_t)BB * 1024 * 32 * 4);

  // sparse structure + norms
  ell_build<<<dim3(NN / 4), dim3(256), 0, stream>>>(A0, ell_col, ell_val, ell_nnz);
  pnorm_kernel<<<dim3(1), dim3(64), 0, stream>>>(p1, p2, invn);

  // ---- encoder level 0 ----
  launch_gemm(x, W1, t0, 4096, 64, 128, 4096l * 64, 4096l * 128, nullptr, 0, stream);
  launch_spmm(ell_col, ell_val, ell_nnz, nullptr, 0, nullptr, 0, t0, 4096l * 128, b1, t1,
              4096l * 128, 4096, 128, 1, stream, nullptr, nullptr, nullptr, nullptr,
              p1, y1, 4096);
  topk_kernel<<<dim3(BB), dim3(1024), 0, stream>>>(y1, 4096, 4096, 2048, nullptr, 0, idx1, 2048,
                                                   inv1, 4096, nullptr, 0, nullptr, 0);

  // ---- encoder level 1 (gather + gate fused into GEMM) ----
  launch_gemm(t1, W2, t0, 2048, 128, 64, 4096l * 128, 2048l * 64, idx1, 2048, stream,
              y1, 4096, invn, 0);
  launch_spmm(ell_col, ell_val, ell_nnz, idx1, 2048, inv1, 4096, t0, 2048l * 64, b2, t1,
              2048l * 64, 2048, 64, 1, stream, nullptr, nullptr, nullptr, nullptr,
              p2, y2, 2048);
  topk_kernel<<<dim3(BB), dim3(1024), 0, stream>>>(y2, 2048, 2048, 1024, idx1, 2048, idx2, 1024,
                                                   inv2, 2048, gidx2, 1024, ginv2, 4096);

  // ---- latent + reparameterize (gather+gate fused; writes mean/logvar to d_out, z to ws) ----
  launch_gemm(t1, Wlat, t0, 1024, 64, 64, 2048l * 64, 1024l * 64, idx2, 1024, stream,
              y2, 2048, invn, 1);
  launch_spmm(ell_col, ell_val, ell_nnz, gidx2, 1024, ginv2, 4096, t0, 1024l * 64, blat, nullptr,
              0, 1024, 64, 3, stream, eps, meanOut, logvarOut, zbuf);

  // ---- decoder ----
  launch_gemm(zbuf, Wd0, t0, 1024, 32, 64, 1024l * 32, 1024l * 64, nullptr, 0, stream);
  launch_spmm(ell_col, ell_val, ell_nnz, gidx2, 1024, ginv2, 4096, t0, 1024l * 64, bd0, t2,
              1024l * 64, 1024, 64, 1, stream);
  // unpool level2->level1 fused into scatter-GEMM (rows not in idx2 -> zero)
  launch_gemm(t2, Wd1, t0, 2048, 64, 96, 1024l * 64, 2048l * 96, inv2, 2048, stream);
  launch_spmm(ell_col, ell_val, ell_nnz, idx1, 2048, inv1, 4096, t0, 2048l * 96, bd1, t1,
              2048l * 96, 2048, 96, 1, stream);
  // unpool level1->level0 fused into scatter-GEMM
  launch_gemm(t1, Wd2, t0, 4096, 96, 128, 2048l * 96, 4096l * 128, inv1, 4096, stream);
  launch_spmm(ell_col, ell_val, ell_nnz, nullptr, 0, nullptr, 0, t0, 4096l * 128, bd2, t2,
              4096l * 128, 4096, 128, 1, stream);
  launch_gemm(t2, Wout, t0, 4096, 128, 64, 4096l * 128, 4096l * 64, nullptr, 0, stream);
  launch_spmm(ell_col, ell_val, ell_nnz, nullptr, 0, nullptr, 0, t0, 4096l * 64, bout, outp,
              4096l * 64, 4096, 64, 2, stream);
}

// Round 16
// 395.281 us; speedup vs baseline: 2.1807x; 1.1436x over previous
//
#include <hip/hip_runtime.h>
#include <hip/hip_bf16.h>

#define NN 4096
#define BB 8
#define LAT 32
#define ELLCAP 128

// ---------------- ELL build v2: float4 loads + wave-prefix compaction ----------------
__global__ __launch_bounds__(256) void ell_build(const float* __restrict__ A,
                                                 int* __restrict__ col,
                                                 float* __restrict__ val,
                                                 int* __restrict__ nnz) {
  int w = threadIdx.x >> 6;
  int lane = threadIdx.x & 63;
  int row = blockIdx.x * 4 + w;
  const float* ar = A + (size_t)row * NN;
  int base = 0;
  for (int i = 0; i < NN; i += 256) {
    float4 a = *(const float4*)&ar[i + lane * 4];
    int cnt = (a.x != 0.f) + (a.y != 0.f) + (a.z != 0.f) + (a.w != 0.f);
    int x = cnt;
#pragma unroll
    for (int off = 1; off < 64; off <<= 1) {
      int y = __shfl_up(x, off, 64);
      if (lane >= off) x += y;
    }
    int total = __shfl(x, 63, 64);
    int p = base + x - cnt;
    float av[4] = {a.x, a.y, a.z, a.w};
#pragma unroll
    for (int u = 0; u < 4; u++) {
      if (av[u] != 0.f) {
        if (p < ELLCAP) {
          col[(size_t)row * ELLCAP + p] = i + lane * 4 + u;
          val[(size_t)row * ELLCAP + p] = av[u];
        }
        p++;
      }
    }
    base += total;
  }
  if (lane == 0) nnz[row] = base < ELLCAP ? base : ELLCAP;
}

// ---------------- p-vector inverse norms ----------------
__global__ void pnorm_kernel(const float* __restrict__ p1, const float* __restrict__ p2,
                             float* __restrict__ invn) {
  int lane = threadIdx.x;
  float s1 = 0.f, s2 = 0.f;
  for (int i = lane; i < 128; i += 64) s1 += p1[i] * p1[i];
  { float v = p2[lane]; s2 = v * v; }
  for (int off = 32; off; off >>= 1) { s1 += __shfl_down(s1, off); s2 += __shfl_down(s2, off); }
  if (lane == 0) { invn[0] = rsqrtf(s1); invn[1] = rsqrtf(s2); }
}

// ---------------- dense GEMM v3: column-contiguous VW cols/thread, XCD-pinned batch ----
// 1D grid ((M/32)*8): b = bid&7, row-tile = bid>>3. Block (32,8).
// Thread owns rows {ty+8i} x cols {tx*VW..tx*VW+VW-1}. kc==32 always (K % 32 == 0).
template <int VW>
__global__ __launch_bounds__(256) void gemm_kernel(
    const float* __restrict__ in, const float* __restrict__ W, float* __restrict__ out,
    int M, int K, long inB, long outB, const int* __restrict__ map, int mapB,
    const float* __restrict__ gateY, long gyB, const float* __restrict__ invn, int which) {
  const int C = VW * 32;
  const int KT = 32, LDI = KT + 4;
  extern __shared__ float lds[];
  float* Wl = lds;            // [KT][C]
  float* inT = lds + KT * C;  // [32][LDI]
  int bid = blockIdx.x;
  int b = bid & 7;
  int row0 = (bid >> 3) * 32;
  const float* inb = in + (size_t)b * inB;
  float* outb = out + (size_t)b * outB;
  const int* mapb = map ? map + (size_t)b * mapB : nullptr;
  int tx = threadIdx.x, ty = threadIdx.y;
  float acc[4][VW];
#pragma unroll
  for (int i = 0; i < 4; i++)
#pragma unroll
    for (int j = 0; j < VW; j++) acc[i][j] = 0.f;
  for (int kt = 0; kt < K; kt += KT) {
    // stage W tile (vector where aligned)
    for (int r = ty; r < KT; r += 8) {
      const float* ws = &W[(size_t)(kt + r) * C + tx * VW];
      float* wd = &Wl[r * C + tx * VW];
      if constexpr (VW == 4) {
        *(float4*)wd = *(const float4*)ws;
      } else if constexpr (VW == 2) {
        *(float2*)wd = *(const float2*)ws;
      } else {
#pragma unroll
        for (int j = 0; j < VW; j++) wd[j] = ws[j];
      }
    }
    // stage input tile (rows with gather/gate)
    for (int r = ty; r < 32; r += 8) {
      int grow = row0 + r;
      int src = grow;
      if (mapb) src = mapb[grow];
      if (src >= 0) {
        float gate = 1.f;
        if (gateY) gate = tanhf(gateY[(size_t)b * gyB + src] * invn[which]);
        const float* ib = inb + (size_t)src * K + kt;
        inT[r * LDI + tx] = ib[tx] * gate;
      } else {
        inT[r * LDI + tx] = 0.f;
      }
    }
    __syncthreads();
    for (int k = 0; k < KT; k += 4) {
      float4 a[4];
#pragma unroll
      for (int i = 0; i < 4; i++) a[i] = *(const float4*)&inT[(ty + i * 8) * LDI + k];
#pragma unroll
      for (int kk = 0; kk < 4; kk++) {
        float w[VW];
        if constexpr (VW == 4) {
          float4 wv = *(const float4*)&Wl[(k + kk) * C + tx * 4];
          w[0] = wv.x; w[1] = wv.y; w[2] = wv.z; w[3] = wv.w;
        } else if constexpr (VW == 2) {
          float2 wv = *(const float2*)&Wl[(k + kk) * C + tx * 2];
          w[0] = wv.x; w[1] = wv.y;
        } else {
#pragma unroll
          for (int j = 0; j < VW; j++) w[j] = Wl[(k + kk) * C + tx * VW + j];
        }
#pragma unroll
        for (int i = 0; i < 4; i++) {
          float av = ((const float*)&a[i])[kk];
#pragma unroll
          for (int j = 0; j < VW; j++) acc[i][j] = fmaf(av, w[j], acc[i][j]);
        }
      }
    }
    __syncthreads();
  }
#pragma unroll
  for (int i = 0; i < 4; i++) {
    int grow = row0 + ty + i * 8;
    float* od = &outb[(size_t)grow * C + tx * VW];
    if constexpr (VW == 4) {
      float4 o = {acc[i][0], acc[i][1], acc[i][2], acc[i][3]};
      *(float4*)od = o;
    } else if constexpr (VW == 2) {
      float2 o = {acc[i][0], acc[i][1]};
      *(float2*)od = o;
    } else {
#pragma unroll
      for (int j = 0; j < VW; j++) od[j] = acc[i][j];
    }
  }
}

// ---------------- SpMM v3: float4 lanes, XCD-pinned batch, 8-way MLP unroll ----------------
template <int C>
__global__ __launch_bounds__(128) void spmm_vec_kernel(
    const int* __restrict__ ecol, const float* __restrict__ evals, const int* __restrict__ ennz,
    const int* __restrict__ rowmap, int rowmapB,
    const int* __restrict__ colinv, int colinvB,
    const float* __restrict__ Y, long yB, const float* __restrict__ bias,
    float* __restrict__ out, long outB, int act,
    const float* __restrict__ eps, float* __restrict__ meanOut,
    float* __restrict__ logvarOut, float* __restrict__ zOut,
    const float* __restrict__ pvec, float* __restrict__ yOut, long yOutB) {
  constexpr int L = C / 4;
  constexpr int R = 128 / L;
  __shared__ int scol[R][ELLCAP];
  __shared__ float sval[R][ELLCAP];
  int bid = blockIdx.x;
  int rb = bid >> 3, b = bid & 7;
  int t = threadIdx.x;
  int rloc = t / L, lane = t % L;
  int row = rb * R + rloc;
  int grow = rowmap ? rowmap[(size_t)b * rowmapB + row] : row;
  int n = ennz[grow];
  const int* cp = ecol + (size_t)grow * ELLCAP;
  const float* vp = evals + (size_t)grow * ELLCAP;
  const int* ci = colinv ? colinv + (size_t)b * colinvB : nullptr;
  for (int e = lane; e < n; e += L) {
    int c = cp[e];
    int li = ci ? ci[c] : c;
    float w = vp[e];
    if (li < 0) { li = 0; w = 0.f; }
    scol[rloc][e] = li;
    sval[rloc][e] = w;
  }
  __syncthreads();
  const float* Yb = Y + (size_t)b * yB;
  float4 acc = {0.f, 0.f, 0.f, 0.f};
  int e = 0;
  for (; e + 8 <= n; e += 8) {
    float4 v[8];
    float w[8];
#pragma unroll
    for (int u = 0; u < 8; u++) {
      w[u] = sval[rloc][e + u];
      v[u] = *(const float4*)&Yb[(size_t)scol[rloc][e + u] * C + lane * 4];
    }
#pragma unroll
    for (int u = 0; u < 8; u++) {
      acc.x = fmaf(w[u], v[u].x, acc.x);
      acc.y = fmaf(w[u], v[u].y, acc.y);
      acc.z = fmaf(w[u], v[u].z, acc.z);
      acc.w = fmaf(w[u], v[u].w, acc.w);
    }
  }
  for (; e < n; e++) {
    float w = sval[rloc][e];
    float4 v = *(const float4*)&Yb[(size_t)scol[rloc][e] * C + lane * 4];
    acc.x = fmaf(w, v.x, acc.x);
    acc.y = fmaf(w, v.y, acc.y);
    acc.z = fmaf(w, v.z, acc.z);
    acc.w = fmaf(w, v.w, acc.w);
  }
  float4 bi = *(const float4*)&bias[lane * 4];
  acc.x += bi.x; acc.y += bi.y; acc.z += bi.z; acc.w += bi.w;
  if (act == 1) {
    acc.x = fmaxf(acc.x, 0.f); acc.y = fmaxf(acc.y, 0.f);
    acc.z = fmaxf(acc.z, 0.f); acc.w = fmaxf(acc.w, 0.f);
  } else if (act == 2) {
    acc.x = fmaxf(acc.x, 0.f) + log1pf(expf(-fabsf(acc.x)));
    acc.y = fmaxf(acc.y, 0.f) + log1pf(expf(-fabsf(acc.y)));
    acc.z = fmaxf(acc.z, 0.f) + log1pf(expf(-fabsf(acc.z)));
    acc.w = fmaxf(acc.w, 0.f) + log1pf(expf(-fabsf(acc.w)));
  } else if (act == 3) {
    int wl = t & 63;
    float4 lv;
    lv.x = __shfl(acc.x, wl + 8, 64);
    lv.y = __shfl(acc.y, wl + 8, 64);
    lv.z = __shfl(acc.z, wl + 8, 64);
    lv.w = __shfl(acc.w, wl + 8, 64);
    size_t o = ((size_t)b * 1024 + row) * LAT;
    if (lane < 8) {
      *(float4*)&meanOut[o + lane * 4] = acc;
      float4 ep = *(const float4*)&eps[o + lane * 4];
      float4 z;
      z.x = fmaf(expf(0.5f * lv.x), ep.x, acc.x);
      z.y = fmaf(expf(0.5f * lv.y), ep.y, acc.y);
      z.z = fmaf(expf(0.5f * lv.z), ep.z, acc.z);
      z.w = fmaf(expf(0.5f * lv.w), ep.w, acc.w);
      *(float4*)&zOut[o + lane * 4] = z;
    } else {
      *(float4*)&logvarOut[o + (lane - 8) * 4] = acc;
    }
    return;
  }
  *(float4*)&out[(size_t)b * outB + (size_t)row * C + lane * 4] = acc;
  if (yOut) {
    float4 pv = *(const float4*)&pvec[lane * 4];
    float part = acc.x * pv.x + acc.y * pv.y + acc.z * pv.z + acc.w * pv.w;
#pragma unroll
    for (int off = L / 2; off > 0; off >>= 1) part += __shfl_down(part, off, 64);
    if (lane == 0) yOut[(size_t)b * yOutB + row] = part;
  }
}

// ---------------- SpMM C=96 vectorized: 24 lanes x float4, 8 rows per 192-thread block ----
__global__ __launch_bounds__(192) void spmm_vec96_kernel(
    const int* __restrict__ ecol, const float* __restrict__ evals, const int* __restrict__ ennz,
    const int* __restrict__ rowmap, int rowmapB,
    const int* __restrict__ colinv, int colinvB,
    const float* __restrict__ Y, long yB, const float* __restrict__ bias,
    float* __restrict__ out, long outB, int act) {
  constexpr int L = 24, R = 8, C = 96;
  __shared__ int scol[R][ELLCAP];
  __shared__ float sval[R][ELLCAP];
  int bid = blockIdx.x;
  int rb = bid >> 3, b = bid & 7;
  int t = threadIdx.x;
  int rloc = t / L, lane = t % L;
  int row = rb * R + rloc;
  int grow = rowmap ? rowmap[(size_t)b * rowmapB + row] : row;
  int n = ennz[grow];
  const int* cp = ecol + (size_t)grow * ELLCAP;
  const float* vp = evals + (size_t)grow * ELLCAP;
  const int* ci = colinv ? colinv + (size_t)b * colinvB : nullptr;
  for (int e = lane; e < n; e += L) {
    int c = cp[e];
    int li = ci ? ci[c] : c;
    float w = vp[e];
    if (li < 0) { li = 0; w = 0.f; }
    scol[rloc][e] = li;
    sval[rloc][e] = w;
  }
  __syncthreads();
  const float* Yb = Y + (size_t)b * yB;
  float4 acc = {0.f, 0.f, 0.f, 0.f};
  int e = 0;
  for (; e + 8 <= n; e += 8) {
    float4 v[8];
    float w[8];
#pragma unroll
    for (int u = 0; u < 8; u++) {
      w[u] = sval[rloc][e + u];
      v[u] = *(const float4*)&Yb[(size_t)scol[rloc][e + u] * C + lane * 4];
    }
#pragma unroll
    for (int u = 0; u < 8; u++) {
      acc.x = fmaf(w[u], v[u].x, acc.x);
      acc.y = fmaf(w[u], v[u].y, acc.y);
      acc.z = fmaf(w[u], v[u].z, acc.z);
      acc.w = fmaf(w[u], v[u].w, acc.w);
    }
  }
  for (; e < n; e++) {
    float w = sval[rloc][e];
    float4 v = *(const float4*)&Yb[(size_t)scol[rloc][e] * C + lane * 4];
    acc.x = fmaf(w, v.x, acc.x);
    acc.y = fmaf(w, v.y, acc.y);
    acc.z = fmaf(w, v.z, acc.z);
    acc.w = fmaf(w, v.w, acc.w);
  }
  float4 bi = *(const float4*)&bias[lane * 4];
  acc.x += bi.x; acc.y += bi.y; acc.z += bi.z; acc.w += bi.w;
  if (act == 1) {
    acc.x = fmaxf(acc.x, 0.f); acc.y = fmaxf(acc.y, 0.f);
    acc.z = fmaxf(acc.z, 0.f); acc.w = fmaxf(acc.w, 0.f);
  }
  *(float4*)&out[(size_t)b * outB + (size_t)row * C + lane * 4] = acc;
}

// ---------------- top-k: radix select + ordered compaction ----------------
__global__ __launch_bounds__(1024) void topk_kernel(
    const float* __restrict__ yIn, int yB, int n, int k,
    const int* __restrict__ prevIdx, int prevB,
    int* __restrict__ idxLoc, int idxB,
    int* __restrict__ invLoc, int invB,
    int* __restrict__ gIdx, int gIdxB,
    int* __restrict__ gInv, int gInvB) {
  __shared__ unsigned int sk[4096];
  __shared__ unsigned int hist[256];
  __shared__ int si[1024];
  __shared__ int s_bin, s_cum;
  int b = blockIdx.x, tid = threadIdx.x;
  const float* y = yIn + (size_t)b * yB;
  for (int i = tid; i < n; i += 1024) {
    unsigned u = __float_as_uint(y[i]);
    sk[i] = (u & 0x80000000u) ? ~u : (u | 0x80000000u);
  }
  int* invb = invLoc + (size_t)b * invB;
  for (int i = tid; i < n; i += 1024) invb[i] = -1;
  int* ginvb = gInv ? gInv + (size_t)b * gInvB : nullptr;
  if (ginvb)
    for (int i = tid; i < NN; i += 1024) ginvb[i] = -1;
  __syncthreads();
  unsigned prefix = 0;
  int kneed = k, countGt = 0;
  for (int shift = 24; shift >= 0; shift -= 8) {
    if (tid < 256) hist[tid] = 0;
    __syncthreads();
    unsigned pmask = (shift == 24) ? 0u : (0xFFFFFFFFu << (shift + 8));
    for (int i = tid; i < n; i += 1024) {
      unsigned key = sk[i];
      if ((key & pmask) == prefix) atomicAdd(&hist[(key >> shift) & 255], 1u);
    }
    __syncthreads();
    if (tid < 256) si[tid] = (int)hist[tid];
    __syncthreads();
    for (int off = 1; off < 256; off <<= 1) {
      int v = 0;
      if (tid < 256) { v = si[tid]; if (tid + off < 256) v += si[tid + off]; }
      __syncthreads();
      if (tid < 256) si[tid] = v;
      __syncthreads();
    }
    if (tid < 256) {
      int cumAbove = (tid < 255) ? si[tid + 1] : 0;
      if (cumAbove < kneed && kneed <= cumAbove + (int)hist[tid]) {
        s_bin = tid;
        s_cum = cumAbove;
      }
    }
    __syncthreads();
    int bin = s_bin, cumAbove = s_cum;
    countGt += cumAbove;
    kneed -= cumAbove;
    prefix |= ((unsigned)bin << shift);
    __syncthreads();
  }
  unsigned tkey = prefix;
  int needEq = k - countGt;
  int ipt = n >> 10;
  int i0 = tid * ipt;
  int locGt = 0, locEq = 0;
  for (int u = 0; u < ipt; u++) {
    unsigned key = sk[i0 + u];
    locGt += (key > tkey) ? 1 : 0;
    locEq += (key == tkey) ? 1 : 0;
  }
  int comb = (locGt << 13) | locEq;
  si[tid] = comb;
  __syncthreads();
  for (int off = 1; off < 1024; off <<= 1) {
    int vv = si[tid];
    int add = (tid >= off) ? si[tid - off] : 0;
    __syncthreads();
    si[tid] = vv + add;
    __syncthreads();
  }
  int excl = si[tid] - comb;
  int gtB = excl >> 13;
  int eqB = excl & 0x1FFF;
  int* idxb = idxLoc + (size_t)b * idxB;
  int* gidxb = gIdx ? gIdx + (size_t)b * gIdxB : nullptr;
  const int* prevb = prevIdx ? prevIdx + (size_t)b * prevB : nullptr;
  for (int u = 0; u < ipt; u++) {
    int i = i0 + u;
    unsigned key = sk[i];
    bool g = key > tkey;
    bool e = (key == tkey);
    bool sel = g || (e && eqB < needEq);
    if (sel) {
      int pos = gtB + (eqB < needEq ? eqB : needEq);
      idxb[pos] = i;
      invb[i] = pos;
      int gi = prevb ? prevb[i] : i;
      if (gidxb) gidxb[pos] = gi;
      if (ginvb) ginvb[gi] = pos;
    }
    gtB += g ? 1 : 0;
    eqB += e ? 1 : 0;
  }
}

// ---------------- host side ----------------
static inline void launch_gemm(const float* in, const float* W, float* out, int M, int K, int C,
                               long inB, long outB, const int* map, int mapB, hipStream_t s,
                               const float* gateY = nullptr, long gyB = 0,
                               const float* invn = nullptr, int which = 0) {
  dim3 g((M / 32) * BB), bl(32, 8);
  size_t lds = (size_t)(32 * C + 32 * 36) * 4;
  if (C == 64)
    gemm_kernel<2><<<g, bl, lds, s>>>(in, W, out, M, K, inB, outB, map, mapB, gateY, gyB, invn, which);
  else if (C == 96)
    gemm_kernel<3><<<g, bl, lds, s>>>(in, W, out, M, K, inB, outB, map, mapB, gateY, gyB, invn, which);
  else
    gemm_kernel<4><<<g, bl, lds, s>>>(in, W, out, M, K, inB, outB, map, mapB, gateY, gyB, invn, which);
}

static inline void launch_spmm(const int* ecol, const float* evals, const int* ennz,
                               const int* rowmap, int rowmapB, const int* colinv, int colinvB,
                               const float* Y, long yB, const float* bias, float* out, long outB,
                               int M, int C, int act, hipStream_t s,
                               const float* eps = nullptr, float* meanOut = nullptr,
                               float* lvOut = nullptr, float* zOut = nullptr,
                               const float* pvec = nullptr, float* yOut = nullptr, long yOutB = 0) {
  if (C == 128) {
    spmm_vec_kernel<128><<<dim3((M / 4) * BB), dim3(128), 0, s>>>(
        ecol, evals, ennz, rowmap, rowmapB, colinv, colinvB, Y, yB, bias, out, outB, act,
        eps, meanOut, lvOut, zOut, pvec, yOut, yOutB);
  } else if (C == 64) {
    spmm_vec_kernel<64><<<dim3((M / 8) * BB), dim3(128), 0, s>>>(
        ecol, evals, ennz, rowmap, rowmapB, colinv, colinvB, Y, yB, bias, out, outB, act,
        eps, meanOut, lvOut, zOut, pvec, yOut, yOutB);
  } else {
    spmm_vec96_kernel<<<dim3((M / 8) * BB), dim3(192), 0, s>>>(
        ecol, evals, ennz, rowmap, rowmapB, colinv, colinvB, Y, yB, bias, out, outB, act);
  }
}

extern "C" void kernel_launch(void* const* d_in, const int* in_sizes, int n_in,
                              void* d_out, int out_size, void* d_ws, size_t ws_size,
                              hipStream_t stream) {
  const float* x = (const float*)d_in[0];
  const float* eps = (const float*)d_in[1];
  const float* A0 = (const float*)d_in[2];
  const float* W1 = (const float*)d_in[3];
  const float* b1 = (const float*)d_in[4];
  const float* p1 = (const float*)d_in[5];
  const float* W2 = (const float*)d_in[6];
  const float* b2 = (const float*)d_in[7];
  const float* p2 = (const float*)d_in[8];
  const float* Wlat = (const float*)d_in[9];
  const float* blat = (const float*)d_in[10];
  const float* Wd0 = (const float*)d_in[11];
  const float* bd0 = (const float*)d_in[12];
  const float* Wd1 = (const float*)d_in[13];
  const float* bd1 = (const float*)d_in[14];
  const float* Wd2 = (const float*)d_in[15];
  const float* bd2 = (const float*)d_in[16];
  const float* Wout = (const float*)d_in[17];
  const float* bout = (const float*)d_in[18];
  float* outp = (float*)d_out;
  float* meanOut = outp + (size_t)BB * 4096 * 64;
  float* logvarOut = meanOut + (size_t)BB * 1024 * 32;

  char* ws = (char*)d_ws;
  size_t off = 0;
  auto alloc = [&](size_t bytes) {
    void* p = ws + off;
    off = (off + bytes + 255) & ~(size_t)255;
    return p;
  };
  int* ell_col = (int*)alloc((size_t)NN * ELLCAP * 4);
  float* ell_val = (float*)alloc((size_t)NN * ELLCAP * 4);
  int* ell_nnz = (int*)alloc((size_t)NN * 4);
  float* invn = (float*)alloc(256);
  float* t0 = (float*)alloc((size_t)BB * 4096 * 128 * 4);
  float* t1 = (float*)alloc((size_t)BB * 4096 * 128 * 4);
  float* t2 = (float*)alloc((size_t)BB * 4096 * 128 * 4);
  float* y1 = (float*)alloc((size_t)BB * 4096 * 4);
  float* y2 = (float*)alloc((size_t)BB * 2048 * 4);
  int* idx1 = (int*)alloc((size_t)BB * 2048 * 4);
  int* inv1 = (int*)alloc((size_t)BB * 4096 * 4);
  int* idx2 = (int*)alloc((size_t)BB * 1024 * 4);
  int* inv2 = (int*)alloc((size_t)BB * 2048 * 4);
  int* gidx2 = (int*)alloc((size_t)BB * 1024 * 4);
  int* ginv2 = (int*)alloc((size_t)BB * 4096 * 4);
  float* zbuf = (float*)alloc((size_t)BB * 1024 * 32 * 4);

  // sparse structure + norms
  ell_build<<<dim3(NN / 4), dim3(256), 0, stream>>>(A0, ell_col, ell_val, ell_nnz);
  pnorm_kernel<<<dim3(1), dim3(64), 0, stream>>>(p1, p2, invn);

  // ---- encoder level 0 ----
  launch_gemm(x, W1, t0, 4096, 64, 128, 4096l * 64, 4096l * 128, nullptr, 0, stream);
  launch_spmm(ell_col, ell_val, ell_nnz, nullptr, 0, nullptr, 0, t0, 4096l * 128, b1, t1,
              4096l * 128, 4096, 128, 1, stream, nullptr, nullptr, nullptr, nullptr,
              p1, y1, 4096);
  topk_kernel<<<dim3(BB), dim3(1024), 0, stream>>>(y1, 4096, 4096, 2048, nullptr, 0, idx1, 2048,
                                                   inv1, 4096, nullptr, 0, nullptr, 0);

  // ---- encoder level 1 (gather + gate fused into GEMM) ----
  launch_gemm(t1, W2, t0, 2048, 128, 64, 4096l * 128, 2048l * 64, idx1, 2048, stream,
              y1, 4096, invn, 0);
  launch_spmm(ell_col, ell_val, ell_nnz, idx1, 2048, inv1, 4096, t0, 2048l * 64, b2, t1,
              2048l * 64, 2048, 64, 1, stream, nullptr, nullptr, nullptr, nullptr,
              p2, y2, 2048);
  topk_kernel<<<dim3(BB), dim3(1024), 0, stream>>>(y2, 2048, 2048, 1024, idx1, 2048, idx2, 1024,
                                                   inv2, 2048, gidx2, 1024, ginv2, 4096);

  // ---- latent + reparameterize (gather+gate fused; writes mean/logvar to d_out, z to ws) ----
  launch_gemm(t1, Wlat, t0, 1024, 64, 64, 2048l * 64, 1024l * 64, idx2, 1024, stream,
              y2, 2048, invn, 1);
  launch_spmm(ell_col, ell_val, ell_nnz, gidx2, 1024, ginv2, 4096, t0, 1024l * 64, blat, nullptr,
              0, 1024, 64, 3, stream, eps, meanOut, logvarOut, zbuf);

  // ---- decoder ----
  launch_gemm(zbuf, Wd0, t0, 1024, 32, 64, 1024l * 32, 1024l * 64, nullptr, 0, stream);
  launch_spmm(ell_col, ell_val, ell_nnz, gidx2, 1024, ginv2, 4096, t0, 1024l * 64, bd0, t2,
              1024l * 64, 1024, 64, 1, stream);
  // unpool level2->level1 fused into scatter-GEMM (rows not in idx2 -> zero)
  launch_gemm(t2, Wd1, t0, 2048, 64, 96, 1024l * 64, 2048l * 96, inv2, 2048, stream);
  launch_spmm(ell_col, ell_val, ell_nnz, idx1, 2048, inv1, 4096, t0, 2048l * 96, bd1, t1,
              2048l * 96, 2048, 96, 1, stream);
  // unpool level1->level0 fused into scatter-GEMM
  launch_gemm(t1, Wd2, t0, 4096, 96, 128, 2048l * 96, 4096l * 128, inv1, 4096, stream);
  launch_spmm(ell_col, ell_val, ell_nnz, nullptr, 0, nullptr, 0, t0, 4096l * 128, bd2, t2,
              4096l * 128, 4096, 128, 1, stream);
  launch_gemm(t2, Wout, t0, 4096, 128, 64, 4096l * 128, 4096l * 64, nullptr, 0, stream);
  launch_spmm(ell_col, ell_val, ell_nnz, nullptr, 0, nullptr, 0, t0, 4096l * 64, bout, outp,
              4096l * 64, 4096, 64, 2, stream);
}